// Round 8
// baseline (366.675 us; speedup 1.0000x reference)
//
#include <hip/hip_runtime.h>
#include <cstdio>

#define NN 50000
#define NE 800000
#define DD 256
#define WS_NEED 113080000UL

__attribute__((constructor)) static void r20_on_load(void) {
    fprintf(stderr, "R20SO_LOADED\n");
    fflush(stderr);
}

__device__ float b2f(unsigned short u) {
    union { unsigned int i; float f; } c;
    c.i = ((unsigned int)u) << 16;
    return c.f;
}
__device__ float clampf(float v) { return fminf(fmaxf(v, -65504.f), 65504.f); }
__device__ float rdF(const void* p, long long idx, int ff) {
    if (ff) return clampf(b2f(((const unsigned short*)p)[idx]));
    return clampf(((const float*)p)[idx]);
}
__device__ unsigned short f2b_rne(float f) {
    union { float f; unsigned int u; } c;
    c.f = f;
    unsigned int r = (c.u + 0x7FFFu + ((c.u >> 16) & 1u)) >> 16;
    return (unsigned short)r;
}

typedef __attribute__((ext_vector_type(8))) short bf16x8;
typedef __attribute__((ext_vector_type(4))) float f32x4;
typedef __attribute__((ext_vector_type(4))) _Float16 f16x4;
typedef __attribute__((ext_vector_type(8))) _Float16 f16x8;

/* per-block x-dtype detect (2KB read, LDS count) — removes cross-kernel
   flags dependency for blocks that need ff locally */
__device__ int detect_ff(const unsigned short* xr) {
    __shared__ int dacc;
    if (threadIdx.x == 0) dacc = 0;
    __syncthreads();
    int g = 0;
    for (int j = 0; j < 4; j++) {
        unsigned short u = xr[(threadIdx.x * 4 + j) * 2];
        int e = (u >> 7) & 0xFF;
        if (u == 0 || u == 0x8000 || (e >= 100 && e <= 140)) g++;
    }
    atomicAdd(&dacc, g);
    __syncthreads();
    return dacc >= 922;
}

/* K1: zero (deg/sums/misc) + dtype detect + W->bf16 + params->fp32.
   blocks 0..195 zero; 196 detect+params+flags; 197..452 cvt_w. */
__global__ void k_setup(int* deg, float* sums, int* misc, const unsigned short* xr,
                        const int* ei, int* flags, const void* W, const void* bias,
                        const void* gamma, const void* beta, unsigned short* Wb,
                        float* pf) {
    int b = blockIdx.x;
    int t = threadIdx.x;
    if (b < 196) {
        int i = b * 256 + t;
        if (i < NN) deg[i] = 0;
        if (i < 2 * DD) sums[i] = 0.f;
        if (i < 16) misc[i] = 0;
        return;
    }
    if (b == 196) {
        __shared__ int acc2;
        if (t == 0) acc2 = 0;
        int ff = detect_ff(xr); /* has its own syncthreads */
        if (ei[2 * t + 1] != 0) atomicAdd(&acc2, 1);
        __syncthreads();
        if (t == 0) {
            flags[0] = ff;
            flags[1] = (acc2 == 0) ? 1 : 0; /* 1 => int64 edges */
        }
        pf[t] = rdF(bias, t, ff);
        pf[DD + t] = rdF(gamma, t, ff);
        pf[2 * DD + t] = rdF(beta, t, ff);
        return;
    }
    int ff = detect_ff(xr);
    int i = (b - 197) * 256 + t;
    Wb[i] = f2b_rne(rdF(W, i, ff));
}

/* K2: edge convert + degree count (one pass over raw edges) */
__global__ void k_edges(const int* raw, const int* flags, int* e32, int* deg) {
    int e = blockIdx.x * 256 + threadIdx.x;
    if (e >= NE) return;
    int f = flags[1];
    int r = f ? raw[2 * e] : raw[e];
    int c = f ? raw[2 * (NE + e)] : raw[NE + e];
    e32[e] = r;
    e32[NE + e] = c;
    if ((unsigned int)r < NN && (unsigned int)c < NN) atomicAdd(&deg[c], 1);
}

/* K3: CSR slot allocation + dinv. Non-canonical base order is fine:
   off[] only needs disjoint contiguous [off[c], off[c]+deg[c]) ranges.
   Block-local LDS scan + one global atomicAdd per block for the base.
   Replaces scan1+scan2+scan3 (2 fewer launches, less work). */
__global__ __launch_bounds__(256) void k_alloc(const int* deg, int* off, int* cursor,
                                               float* dinv, int* gcur) {
    __shared__ int sm[256];
    __shared__ int sbase;
    int tid = threadIdx.x;
    int i = blockIdx.x * 256 + tid;
    int v = (i < NN) ? deg[i] : 0;
    sm[tid] = v;
    __syncthreads();
    for (int s = 1; s < 256; s <<= 1) {
        int t = (tid >= s) ? sm[tid - s] : 0;
        __syncthreads();
        sm[tid] += t;
        __syncthreads();
    }
    if (tid == 255) sbase = atomicAdd(gcur, sm[255]);
    __syncthreads();
    if (i < NN) {
        int o = sbase + sm[tid] - v;
        off[i] = o;
        cursor[i] = o;
        dinv[i] = rsqrtf((float)(v + 1));
    }
}

/* K4: fused GEMM (blocks 0..3127) + CSR fill (blocks 3128..6252).
   Independent work, both ready after k_alloc; fill overlaps gemm tail.
   GEMM: B staged in LDS, 528B row pitch (R19). h' = dinv[n]*x@W^T, fp16.
   C/D: col = lane&15, row = (lane>>4)*4 + reg  (m89-verified mapping) */
#define WP 264 /* LDS row pitch in shorts (512B data + 16B pad) */
__global__ __launch_bounds__(256) void k_gf(const void* x, const int* flags,
                                            const unsigned short* Wb,
                                            const float* dinv, _Float16* h,
                                            const int* erow, const int* ecol,
                                            int* cursor, int* csrc) {
    if (blockIdx.x >= 3128) { /* fill part */
        int e = (blockIdx.x - 3128) * 256 + threadIdx.x;
        if (e < NE) {
            unsigned int c = (unsigned int)ecol[e];
            unsigned int r = (unsigned int)erow[e];
            if (c < NN && r < NN) {
                int slot = atomicAdd(&cursor[c], 1);
                if ((unsigned int)slot < NE) csrc[slot] = (int)r;
            }
        }
        return;
    }
    __shared__ unsigned short wlds[64 * WP]; /* 33792 B */
    int t = threadIdx.x;
    int rt = blockIdx.x >> 2;   /* row-tile 0..781 */
    int ctile = blockIdx.x & 3; /* col-tile 0..3 */

    const unsigned short* wsrc = Wb + ctile * 64 * DD;
#pragma unroll
    for (int i = 0; i < 8; i++) {
        int c = t + i * 256;
        int row = c >> 5;
        int off = (c & 31) * 8;
        bf16x8 v = *(const bf16x8*)(wsrc + row * DD + off);
        *(bf16x8*)(&wlds[row * WP + off]) = v;
    }
    __syncthreads();

    int wave = t >> 6;
    int lane = t & 63;
    int rw = rt * 4 + wave;
    if (rw >= 3125) return;
    int r0 = rw * 16;
    int l15 = lane & 15;
    int kq = lane >> 4;

    bf16x8 a[8];
    int ff = flags[0];
    if (ff) {
        const unsigned short* p =
            (const unsigned short*)x + (unsigned long long)(r0 + l15) * DD + kq * 8;
#pragma unroll
        for (int k = 0; k < 8; k++)
            a[k] = *(const bf16x8*)(p + k * 32);
    } else {
        const float* p = (const float*)x + (unsigned long long)(r0 + l15) * DD + kq * 8;
#pragma unroll
        for (int k = 0; k < 8; k++) {
#pragma unroll
            for (int j = 0; j < 8; j++)
                a[k][j] = (short)f2b_rne(p[k * 32 + j]);
        }
    }

    float dv[4];
#pragma unroll
    for (int j = 0; j < 4; j++) dv[j] = dinv[r0 + kq * 4 + j];

    f32x4 acc[4];
#pragma unroll
    for (int ct = 0; ct < 4; ct++) acc[ct] = (f32x4){0.f, 0.f, 0.f, 0.f};

#pragma unroll
    for (int k = 0; k < 8; k++) {
        bf16x8 bfr[4];
#pragma unroll
        for (int ct = 0; ct < 4; ct++)
            bfr[ct] = *(const bf16x8*)(&wlds[(ct * 16 + l15) * WP + kq * 8 + k * 32]);
#pragma unroll
        for (int ct = 0; ct < 4; ct++)
            acc[ct] = __builtin_amdgcn_mfma_f32_16x16x32_bf16(a[k], bfr[ct], acc[ct],
                                                              0, 0, 0);
    }

#pragma unroll
    for (int ct = 0; ct < 4; ct++) {
        _Float16* op = h + (unsigned long long)(r0 + kq * 4) * DD + ctile * 64 +
                       ct * 16 + l15;
#pragma unroll
        for (int j = 0; j < 4; j++)
            op[(unsigned long long)j * DD] = (_Float16)(acc[ct][j] * dv[j]);
    }
}

/* K5: aggregate + bias -> fp16 agg. one node per wave, 8-deep ILP unroll. */
__global__ __launch_bounds__(256) void g_agg(const _Float16* h, const float* dinv,
                                             const int* off, const int* deg,
                                             const int* csrc, const float* pf,
                                             _Float16* agg) {
    int lane = threadIdx.x & 63;
    int n = blockIdx.x * 4 + (threadIdx.x >> 6);
    int f0 = lane * 4;
    int s = __builtin_amdgcn_readfirstlane(off[n]);
    int cnt = __builtin_amdgcn_readfirstlane(deg[n]);
    float dn = dinv[n];
    f16x4 hv = *(const f16x4*)(h + (unsigned long long)n * DD + f0);
    float a0 = (float)hv[0];
    float a1 = (float)hv[1];
    float a2 = (float)hv[2];
    float a3 = (float)hv[3];
    const int* ip = csrc + s;
    int k = 0;
    for (; k + 8 <= cnt; k += 8) {
        int i0 = ip[k + 0], i1 = ip[k + 1], i2 = ip[k + 2], i3 = ip[k + 3];
        int i4 = ip[k + 4], i5 = ip[k + 5], i6 = ip[k + 6], i7 = ip[k + 7];
        f16x4 v0 = *(const f16x4*)(h + (unsigned long long)i0 * DD + f0);
        f16x4 v1 = *(const f16x4*)(h + (unsigned long long)i1 * DD + f0);
        f16x4 v2 = *(const f16x4*)(h + (unsigned long long)i2 * DD + f0);
        f16x4 v3 = *(const f16x4*)(h + (unsigned long long)i3 * DD + f0);
        f16x4 v4 = *(const f16x4*)(h + (unsigned long long)i4 * DD + f0);
        f16x4 v5 = *(const f16x4*)(h + (unsigned long long)i5 * DD + f0);
        f16x4 v6 = *(const f16x4*)(h + (unsigned long long)i6 * DD + f0);
        f16x4 v7 = *(const f16x4*)(h + (unsigned long long)i7 * DD + f0);
        a0 += (((float)v0[0] + (float)v1[0]) + ((float)v2[0] + (float)v3[0])) +
              (((float)v4[0] + (float)v5[0]) + ((float)v6[0] + (float)v7[0]));
        a1 += (((float)v0[1] + (float)v1[1]) + ((float)v2[1] + (float)v3[1])) +
              (((float)v4[1] + (float)v5[1]) + ((float)v6[1] + (float)v7[1]));
        a2 += (((float)v0[2] + (float)v1[2]) + ((float)v2[2] + (float)v3[2])) +
              (((float)v4[2] + (float)v5[2]) + ((float)v6[2] + (float)v7[2]));
        a3 += (((float)v0[3] + (float)v1[3]) + ((float)v2[3] + (float)v3[3])) +
              (((float)v4[3] + (float)v5[3]) + ((float)v6[3] + (float)v7[3]));
    }
    for (; k + 4 <= cnt; k += 4) {
        int i0 = ip[k + 0], i1 = ip[k + 1], i2 = ip[k + 2], i3 = ip[k + 3];
        f16x4 v0 = *(const f16x4*)(h + (unsigned long long)i0 * DD + f0);
        f16x4 v1 = *(const f16x4*)(h + (unsigned long long)i1 * DD + f0);
        f16x4 v2 = *(const f16x4*)(h + (unsigned long long)i2 * DD + f0);
        f16x4 v3 = *(const f16x4*)(h + (unsigned long long)i3 * DD + f0);
        a0 += ((float)v0[0] + (float)v1[0]) + ((float)v2[0] + (float)v3[0]);
        a1 += ((float)v0[1] + (float)v1[1]) + ((float)v2[1] + (float)v3[1]);
        a2 += ((float)v0[2] + (float)v1[2]) + ((float)v2[2] + (float)v3[2]);
        a3 += ((float)v0[3] + (float)v1[3]) + ((float)v2[3] + (float)v3[3]);
    }
    for (; k < cnt; k++) {
        int i0 = ip[k];
        f16x4 v0 = *(const f16x4*)(h + (unsigned long long)i0 * DD + f0);
        a0 += (float)v0[0];
        a1 += (float)v0[1];
        a2 += (float)v0[2];
        a3 += (float)v0[3];
    }
    f16x4 o;
    o[0] = (_Float16)(dn * a0 + pf[f0 + 0]);
    o[1] = (_Float16)(dn * a1 + pf[f0 + 1]);
    o[2] = (_Float16)(dn * a2 + pf[f0 + 2]);
    o[3] = (_Float16)(dn * a3 + pf[f0 + 3]);
    *(f16x4*)(agg + (unsigned long long)n * DD + f0) = o;
}

/* K6: stats + fin fused (threadfence+ticket last-block pattern).
   Cross-XCD reads of atomically-written sums use agent-scope atomic loads. */
__global__ __launch_bounds__(256) void k_stats(const _Float16* agg, float* sums,
                                               const float* pf, float* ss, int* done) {
    int t = threadIdx.x;
    float s = 0.f;
    float s2 = 0.f;
    for (int n = blockIdx.x; n < NN; n += 256) {
        float v = (float)agg[(unsigned long long)n * DD + t];
        s += v;
        s2 += v * v;
    }
    atomicAdd(&sums[t], s);
    atomicAdd(&sums[DD + t], s2);
    __threadfence();
    __syncthreads();
    __shared__ int lastf;
    if (t == 0) lastf = (atomicAdd(done, 1) == 255) ? 1 : 0;
    __syncthreads();
    if (lastf) {
        float sv = __hip_atomic_load(&sums[t], __ATOMIC_RELAXED,
                                     __HIP_MEMORY_SCOPE_AGENT);
        float sv2 = __hip_atomic_load(&sums[DD + t], __ATOMIC_RELAXED,
                                      __HIP_MEMORY_SCOPE_AGENT);
        float mean = sv * (1.0f / NN);
        float var = fmaxf(sv2 * (1.0f / NN) - mean * mean, 0.f);
        float sc = pf[DD + t] * rsqrtf(var + 1e-5f);
        ss[t] = sc;
        ss[DD + t] = pf[2 * DD + t] - mean * sc;
    }
}

/* K7: BN + ReLU: fp16 agg -> fp32 out. 8 elems/thread, grid 6250. */
__global__ void DenseGCNLayer_2937757631000_kernel(const _Float16* agg, const float* ss,
                                                   float* out) {
    int t = threadIdx.x;
    unsigned long long base =
        (unsigned long long)blockIdx.x * 2048 + (unsigned int)t * 8;
    int f = (int)(base & 255);
    f16x8 v = *(const f16x8*)(agg + base);
    f32x4 o0, o1;
#pragma unroll
    for (int j = 0; j < 4; j++)
        o0[j] = fmaxf(ss[f + j] * (float)v[j] + ss[DD + f + j], 0.f);
#pragma unroll
    for (int j = 0; j < 4; j++)
        o1[j] = fmaxf(ss[f + 4 + j] * (float)v[4 + j] + ss[DD + f + 4 + j], 0.f);
    *(f32x4*)(out + base) = o0;
    *(f32x4*)(out + base + 4) = o1;
}

extern "C" void kernel_launch(void* const* d_in, const int* in_sizes, int n_in,
                              void* d_out, int out_size, void* d_ws, size_t ws_size,
                              hipStream_t stream) {
    const void* x = d_in[0];
    const int* ei = (const int*)d_in[1];
    const void* W = d_in[2];
    const void* bias = d_in[3];
    const void* gamma = d_in[4];
    const void* beta = d_in[5];
    char* ws = (char*)d_ws;
    float* out = (float*)d_out;

    _Float16* h = (_Float16*)(ws + 0UL);          /* 25.6 MB fp16 */
    _Float16* agg = (_Float16*)(ws + 51200000UL); /* 25.6 MB fp16 */
    int* e32 = (int*)(ws + 102400000UL);          /* 6.4 MB */
    int* csrc = (int*)(ws + 108800000UL);         /* 3.2 MB */
    unsigned short* Wb = (unsigned short*)(ws + 112000000UL); /* 128 KB bf16 */
    int* deg = (int*)(ws + 112262144UL);
    float* dinv = (float*)(ws + 112462336UL);
    int* off = (int*)(ws + 112662528UL);
    int* cursor = (int*)(ws + 112862720UL);
    int* misc = (int*)(ws + 113063936UL); /* gcur, done, ... (16 ints) */
    float* pf = (float*)(ws + 113064960UL);
    float* sums = (float*)(ws + 113068032UL);
    float* ss = (float*)(ws + 113070080UL);
    int* flags = (int*)(ws + 113072128UL);
    const int* erow = e32;
    const int* ecol = e32 + NE;

    if (ws_size < WS_NEED) {
        fprintf(stderr, "R20_WS_SMALL %zu\n", ws_size);
        fflush(stderr);
        return;
    }

    k_setup<<<453, 256, 0, stream>>>(deg, sums, misc, (const unsigned short*)x, ei,
                                     flags, W, bias, gamma, beta, Wb, pf);
    k_edges<<<3125, 256, 0, stream>>>(ei, flags, e32, deg);
    k_alloc<<<196, 256, 0, stream>>>(deg, off, cursor, dinv, &misc[0]);
    k_gf<<<6253, 256, 0, stream>>>(x, flags, Wb, dinv, h, erow, ecol, cursor, csrc);
    g_agg<<<12500, 256, 0, stream>>>(h, dinv, off, deg, csrc, pf, agg);
    k_stats<<<256, 256, 0, stream>>>(agg, sums, pf, ss, &misc[1]);
    DenseGCNLayer_2937757631000_kernel<<<6250, 256, 0, stream>>>(agg, ss, out);
}

// Round 9
// 348.609 us; speedup vs baseline: 1.0518x; 1.0518x over previous
//
#include <hip/hip_runtime.h>
#include <cstdio>

#define NN 50000
#define NE 800000
#define DD 256
#define WS_NEED 113080000UL

__attribute__((constructor)) static void r21_on_load(void) {
    fprintf(stderr, "R21SO_LOADED\n");
    fflush(stderr);
}

__device__ float b2f(unsigned short u) {
    union { unsigned int i; float f; } c;
    c.i = ((unsigned int)u) << 16;
    return c.f;
}
__device__ float clampf(float v) { return fminf(fmaxf(v, -65504.f), 65504.f); }
__device__ float rdF(const void* p, long long idx, int ff) {
    if (ff) return clampf(b2f(((const unsigned short*)p)[idx]));
    return clampf(((const float*)p)[idx]);
}
__device__ unsigned short f2b_rne(float f) {
    union { float f; unsigned int u; } c;
    c.f = f;
    unsigned int r = (c.u + 0x7FFFu + ((c.u >> 16) & 1u)) >> 16;
    return (unsigned short)r;
}

typedef __attribute__((ext_vector_type(8))) short bf16x8;
typedef __attribute__((ext_vector_type(4))) float f32x4;
typedef __attribute__((ext_vector_type(4))) _Float16 f16x4;
typedef __attribute__((ext_vector_type(8))) _Float16 f16x8;

/* per-block x-dtype detect (2KB read, LDS count) */
__device__ int detect_ff(const unsigned short* xr) {
    __shared__ int dacc;
    if (threadIdx.x == 0) dacc = 0;
    __syncthreads();
    int g = 0;
    for (int j = 0; j < 4; j++) {
        unsigned short u = xr[(threadIdx.x * 4 + j) * 2];
        int e = (u >> 7) & 0xFF;
        if (u == 0 || u == 0x8000 || (e >= 100 && e <= 140)) g++;
    }
    atomicAdd(&dacc, g);
    __syncthreads();
    return dacc >= 922;
}

/* K1: zero (deg/sums/misc) + dtype detect + W->bf16 + params->fp32. */
__global__ void k_setup(int* deg, float* sums, int* misc, const unsigned short* xr,
                        const int* ei, int* flags, const void* W, const void* bias,
                        const void* gamma, const void* beta, unsigned short* Wb,
                        float* pf) {
    int b = blockIdx.x;
    int t = threadIdx.x;
    if (b < 196) {
        int i = b * 256 + t;
        if (i < NN) deg[i] = 0;
        if (i < 2 * DD) sums[i] = 0.f;
        if (i < 16) misc[i] = 0;
        return;
    }
    if (b == 196) {
        __shared__ int acc2;
        if (t == 0) acc2 = 0;
        int ff = detect_ff(xr); /* has its own syncthreads */
        if (ei[2 * t + 1] != 0) atomicAdd(&acc2, 1);
        __syncthreads();
        if (t == 0) {
            flags[0] = ff;
            flags[1] = (acc2 == 0) ? 1 : 0; /* 1 => int64 edges */
        }
        pf[t] = rdF(bias, t, ff);
        pf[DD + t] = rdF(gamma, t, ff);
        pf[2 * DD + t] = rdF(beta, t, ff);
        return;
    }
    int ff = detect_ff(xr);
    int i = (b - 197) * 256 + t;
    Wb[i] = f2b_rne(rdF(W, i, ff));
}

/* K2: degree count, reading raw edges directly (no e32 intermediate) */
__global__ void k_edges(const int* raw, const int* flags, int* deg) {
    int e = blockIdx.x * 256 + threadIdx.x;
    if (e >= NE) return;
    int f = flags[1];
    int r = f ? raw[2 * e] : raw[e];
    int c = f ? raw[2 * (NE + e)] : raw[NE + e];
    if ((unsigned int)r < NN && (unsigned int)c < NN) atomicAdd(&deg[c], 1);
}

/* K3: CSR slot allocation + dinv (block-local scan + global atomic base). */
__global__ __launch_bounds__(256) void k_alloc(const int* deg, int* off, int* cursor,
                                               float* dinv, int* gcur) {
    __shared__ int sm[256];
    __shared__ int sbase;
    int tid = threadIdx.x;
    int i = blockIdx.x * 256 + tid;
    int v = (i < NN) ? deg[i] : 0;
    sm[tid] = v;
    __syncthreads();
    for (int s = 1; s < 256; s <<= 1) {
        int t = (tid >= s) ? sm[tid - s] : 0;
        __syncthreads();
        sm[tid] += t;
        __syncthreads();
    }
    if (tid == 255) sbase = atomicAdd(gcur, sm[255]);
    __syncthreads();
    if (i < NN) {
        int o = sbase + sm[tid] - v;
        off[i] = o;
        cursor[i] = o;
        dinv[i] = rsqrtf((float)(v + 1));
    }
}

/* K4: MFMA GEMM, 128-col tiles (R21: halves x re-reads vs 64-col R19).
   Block = 4 waves x 16 rows = 64 rows, 128 cols. W-tile 128rows x 256k bf16
   staged in LDS with 528B pitch = 67.6 KB -> 2 blocks/CU, 8 waves.
   h' = dinv[n] * (x @ W^T), fp32 acc, fp16 store.
   C/D: col = lane&15, row = (lane>>4)*4 + reg  (m89-verified mapping) */
#define WP 264 /* LDS row pitch in shorts (512B data + 16B pad) */
__global__ __launch_bounds__(256) void k_gemm(const void* x, const int* flags,
                                              const unsigned short* Wb,
                                              const float* dinv, _Float16* h) {
    __shared__ unsigned short wlds[128 * WP]; /* 67584 B */
    int t = threadIdx.x;
    int rt = blockIdx.x >> 1;   /* row-tile 0..781 */
    int ctile = blockIdx.x & 1; /* col-tile 0..1 (128 cols each) */

    /* stage: 128 rows x 256 shorts = 4096 16B-chunks; 256 thr x 16 iters */
    const unsigned short* wsrc = Wb + ctile * 128 * DD;
#pragma unroll
    for (int i = 0; i < 16; i++) {
        int c = t + i * 256;
        int row = c >> 5;
        int off = (c & 31) * 8;
        bf16x8 v = *(const bf16x8*)(wsrc + row * DD + off);
        *(bf16x8*)(&wlds[row * WP + off]) = v;
    }
    __syncthreads();

    int wave = t >> 6;
    int lane = t & 63;
    int rw = rt * 4 + wave;
    if (rw >= 3125) return; /* after barrier: safe */
    int r0 = rw * 16;
    int l15 = lane & 15;
    int kq = lane >> 4;

    bf16x8 a[8];
    int ff = flags[0];
    if (ff) {
        const unsigned short* p =
            (const unsigned short*)x + (unsigned long long)(r0 + l15) * DD + kq * 8;
#pragma unroll
        for (int k = 0; k < 8; k++)
            a[k] = *(const bf16x8*)(p + k * 32);
    } else {
        const float* p = (const float*)x + (unsigned long long)(r0 + l15) * DD + kq * 8;
#pragma unroll
        for (int k = 0; k < 8; k++) {
#pragma unroll
            for (int j = 0; j < 8; j++)
                a[k][j] = (short)f2b_rne(p[k * 32 + j]);
        }
    }

    float dv[4];
#pragma unroll
    for (int j = 0; j < 4; j++) dv[j] = dinv[r0 + kq * 4 + j];

    f32x4 acc[8];
#pragma unroll
    for (int ct = 0; ct < 8; ct++) acc[ct] = (f32x4){0.f, 0.f, 0.f, 0.f};

#pragma unroll
    for (int k = 0; k < 8; k++) {
        bf16x8 bfr[8];
#pragma unroll
        for (int ct = 0; ct < 8; ct++)
            bfr[ct] = *(const bf16x8*)(&wlds[(ct * 16 + l15) * WP + kq * 8 + k * 32]);
#pragma unroll
        for (int ct = 0; ct < 8; ct++)
            acc[ct] = __builtin_amdgcn_mfma_f32_16x16x32_bf16(a[k], bfr[ct], acc[ct],
                                                              0, 0, 0);
    }

#pragma unroll
    for (int ct = 0; ct < 8; ct++) {
        _Float16* op = h + (unsigned long long)(r0 + kq * 4) * DD + ctile * 128 +
                       ct * 16 + l15;
#pragma unroll
        for (int j = 0; j < 4; j++)
            op[(unsigned long long)j * DD] = (_Float16)(acc[ct][j] * dv[j]);
    }
}

/* K5: CSR fill, reading raw edges directly. No LDS -> full occupancy. */
__global__ void k_fill(const int* raw, const int* flags, int* cursor, int* csrc) {
    int e = blockIdx.x * 256 + threadIdx.x;
    if (e >= NE) return;
    int f = flags[1];
    int r = f ? raw[2 * e] : raw[e];
    int c = f ? raw[2 * (NE + e)] : raw[NE + e];
    if ((unsigned int)c < NN && (unsigned int)r < NN) {
        int slot = atomicAdd(&cursor[c], 1);
        if ((unsigned int)slot < NE) csrc[slot] = r;
    }
}

/* K6: aggregate + bias -> fp16 agg. one node per wave, 8-deep ILP unroll. */
__global__ __launch_bounds__(256) void g_agg(const _Float16* h, const float* dinv,
                                             const int* off, const int* deg,
                                             const int* csrc, const float* pf,
                                             _Float16* agg) {
    int lane = threadIdx.x & 63;
    int n = blockIdx.x * 4 + (threadIdx.x >> 6);
    int f0 = lane * 4;
    int s = __builtin_amdgcn_readfirstlane(off[n]);
    int cnt = __builtin_amdgcn_readfirstlane(deg[n]);
    float dn = dinv[n];
    f16x4 hv = *(const f16x4*)(h + (unsigned long long)n * DD + f0);
    float a0 = (float)hv[0];
    float a1 = (float)hv[1];
    float a2 = (float)hv[2];
    float a3 = (float)hv[3];
    const int* ip = csrc + s;
    int k = 0;
    for (; k + 8 <= cnt; k += 8) {
        int i0 = ip[k + 0], i1 = ip[k + 1], i2 = ip[k + 2], i3 = ip[k + 3];
        int i4 = ip[k + 4], i5 = ip[k + 5], i6 = ip[k + 6], i7 = ip[k + 7];
        f16x4 v0 = *(const f16x4*)(h + (unsigned long long)i0 * DD + f0);
        f16x4 v1 = *(const f16x4*)(h + (unsigned long long)i1 * DD + f0);
        f16x4 v2 = *(const f16x4*)(h + (unsigned long long)i2 * DD + f0);
        f16x4 v3 = *(const f16x4*)(h + (unsigned long long)i3 * DD + f0);
        f16x4 v4 = *(const f16x4*)(h + (unsigned long long)i4 * DD + f0);
        f16x4 v5 = *(const f16x4*)(h + (unsigned long long)i5 * DD + f0);
        f16x4 v6 = *(const f16x4*)(h + (unsigned long long)i6 * DD + f0);
        f16x4 v7 = *(const f16x4*)(h + (unsigned long long)i7 * DD + f0);
        a0 += (((float)v0[0] + (float)v1[0]) + ((float)v2[0] + (float)v3[0])) +
              (((float)v4[0] + (float)v5[0]) + ((float)v6[0] + (float)v7[0]));
        a1 += (((float)v0[1] + (float)v1[1]) + ((float)v2[1] + (float)v3[1])) +
              (((float)v4[1] + (float)v5[1]) + ((float)v6[1] + (float)v7[1]));
        a2 += (((float)v0[2] + (float)v1[2]) + ((float)v2[2] + (float)v3[2])) +
              (((float)v4[2] + (float)v5[2]) + ((float)v6[2] + (float)v7[2]));
        a3 += (((float)v0[3] + (float)v1[3]) + ((float)v2[3] + (float)v3[3])) +
              (((float)v4[3] + (float)v5[3]) + ((float)v6[3] + (float)v7[3]));
    }
    for (; k + 4 <= cnt; k += 4) {
        int i0 = ip[k + 0], i1 = ip[k + 1], i2 = ip[k + 2], i3 = ip[k + 3];
        f16x4 v0 = *(const f16x4*)(h + (unsigned long long)i0 * DD + f0);
        f16x4 v1 = *(const f16x4*)(h + (unsigned long long)i1 * DD + f0);
        f16x4 v2 = *(const f16x4*)(h + (unsigned long long)i2 * DD + f0);
        f16x4 v3 = *(const f16x4*)(h + (unsigned long long)i3 * DD + f0);
        a0 += ((float)v0[0] + (float)v1[0]) + ((float)v2[0] + (float)v3[0]);
        a1 += ((float)v0[1] + (float)v1[1]) + ((float)v2[1] + (float)v3[1]);
        a2 += ((float)v0[2] + (float)v1[2]) + ((float)v2[2] + (float)v3[2]);
        a3 += ((float)v0[3] + (float)v1[3]) + ((float)v2[3] + (float)v3[3]);
    }
    for (; k < cnt; k++) {
        int i0 = ip[k];
        f16x4 v0 = *(const f16x4*)(h + (unsigned long long)i0 * DD + f0);
        a0 += (float)v0[0];
        a1 += (float)v0[1];
        a2 += (float)v0[2];
        a3 += (float)v0[3];
    }
    f16x4 o;
    o[0] = (_Float16)(dn * a0 + pf[f0 + 0]);
    o[1] = (_Float16)(dn * a1 + pf[f0 + 1]);
    o[2] = (_Float16)(dn * a2 + pf[f0 + 2]);
    o[3] = (_Float16)(dn * a3 + pf[f0 + 3]);
    *(f16x4*)(agg + (unsigned long long)n * DD + f0) = o;
}

/* K7: stats + fin fused (threadfence+ticket last-block pattern). */
__global__ __launch_bounds__(256) void k_stats(const _Float16* agg, float* sums,
                                               const float* pf, float* ss, int* done) {
    int t = threadIdx.x;
    float s = 0.f;
    float s2 = 0.f;
    for (int n = blockIdx.x; n < NN; n += 256) {
        float v = (float)agg[(unsigned long long)n * DD + t];
        s += v;
        s2 += v * v;
    }
    atomicAdd(&sums[t], s);
    atomicAdd(&sums[DD + t], s2);
    __threadfence();
    __syncthreads();
    __shared__ int lastf;
    if (t == 0) lastf = (atomicAdd(done, 1) == 255) ? 1 : 0;
    __syncthreads();
    if (lastf) {
        float sv = __hip_atomic_load(&sums[t], __ATOMIC_RELAXED,
                                     __HIP_MEMORY_SCOPE_AGENT);
        float sv2 = __hip_atomic_load(&sums[DD + t], __ATOMIC_RELAXED,
                                      __HIP_MEMORY_SCOPE_AGENT);
        float mean = sv * (1.0f / NN);
        float var = fmaxf(sv2 * (1.0f / NN) - mean * mean, 0.f);
        float sc = pf[DD + t] * rsqrtf(var + 1e-5f);
        ss[t] = sc;
        ss[DD + t] = pf[2 * DD + t] - mean * sc;
    }
}

/* K8: BN + ReLU: fp16 agg -> fp32 out. 8 elems/thread, grid 6250. */
__global__ void DenseGCNLayer_2937757631000_kernel(const _Float16* agg, const float* ss,
                                                   float* out) {
    int t = threadIdx.x;
    unsigned long long base =
        (unsigned long long)blockIdx.x * 2048 + (unsigned int)t * 8;
    int f = (int)(base & 255);
    f16x8 v = *(const f16x8*)(agg + base);
    f32x4 o0, o1;
#pragma unroll
    for (int j = 0; j < 4; j++)
        o0[j] = fmaxf(ss[f + j] * (float)v[j] + ss[DD + f + j], 0.f);
#pragma unroll
    for (int j = 0; j < 4; j++)
        o1[j] = fmaxf(ss[f + 4 + j] * (float)v[4 + j] + ss[DD + f + 4 + j], 0.f);
    *(f32x4*)(out + base) = o0;
    *(f32x4*)(out + base + 4) = o1;
}

extern "C" void kernel_launch(void* const* d_in, const int* in_sizes, int n_in,
                              void* d_out, int out_size, void* d_ws, size_t ws_size,
                              hipStream_t stream) {
    const void* x = d_in[0];
    const int* ei = (const int*)d_in[1];
    const void* W = d_in[2];
    const void* bias = d_in[3];
    const void* gamma = d_in[4];
    const void* beta = d_in[5];
    char* ws = (char*)d_ws;
    float* out = (float*)d_out;

    _Float16* h = (_Float16*)(ws + 0UL);          /* 25.6 MB fp16 */
    _Float16* agg = (_Float16*)(ws + 51200000UL); /* 25.6 MB fp16 */
    int* csrc = (int*)(ws + 108800000UL);         /* 3.2 MB */
    unsigned short* Wb = (unsigned short*)(ws + 112000000UL); /* 128 KB bf16 */
    int* deg = (int*)(ws + 112262144UL);
    float* dinv = (float*)(ws + 112462336UL);
    int* off = (int*)(ws + 112662528UL);
    int* cursor = (int*)(ws + 112862720UL);
    int* misc = (int*)(ws + 113063936UL); /* gcur, done, ... (16 ints) */
    float* pf = (float*)(ws + 113064960UL);
    float* sums = (float*)(ws + 113068032UL);
    float* ss = (float*)(ws + 113070080UL);
    int* flags = (int*)(ws + 113072128UL);

    if (ws_size < WS_NEED) {
        fprintf(stderr, "R21_WS_SMALL %zu\n", ws_size);
        fflush(stderr);
        return;
    }

    k_setup<<<453, 256, 0, stream>>>(deg, sums, misc, (const unsigned short*)x, ei,
                                     flags, W, bias, gamma, beta, Wb, pf);
    k_edges<<<3125, 256, 0, stream>>>(ei, flags, deg);
    k_alloc<<<196, 256, 0, stream>>>(deg, off, cursor, dinv, &misc[0]);
    k_gemm<<<1564, 256, 0, stream>>>(x, flags, Wb, dinv, h);
    k_fill<<<3125, 256, 0, stream>>>(ei, flags, cursor, csrc);
    g_agg<<<12500, 256, 0, stream>>>(h, dinv, off, deg, csrc, pf, agg);
    k_stats<<<256, 256, 0, stream>>>(agg, sums, pf, ss, &misc[1]);
    DenseGCNLayer_2937757631000_kernel<<<6250, 256, 0, stream>>>(agg, ss, out);
}

// Round 10
// 341.708 us; speedup vs baseline: 1.0731x; 1.0202x over previous
//
#include <hip/hip_runtime.h>
#include <cstdio>

#define NN 50000
#define NE 800000
#define DD 256
#define WS_NEED 113080000UL

__attribute__((constructor)) static void r22_on_load(void) {
    fprintf(stderr, "R22SO_LOADED\n");
    fflush(stderr);
}

__device__ float b2f(unsigned short u) {
    union { unsigned int i; float f; } c;
    c.i = ((unsigned int)u) << 16;
    return c.f;
}
__device__ float clampf(float v) { return fminf(fmaxf(v, -65504.f), 65504.f); }
__device__ float rdF(const void* p, long long idx, int ff) {
    if (ff) return clampf(b2f(((const unsigned short*)p)[idx]));
    return clampf(((const float*)p)[idx]);
}
__device__ unsigned short f2b_rne(float f) {
    union { float f; unsigned int u; } c;
    c.f = f;
    unsigned int r = (c.u + 0x7FFFu + ((c.u >> 16) & 1u)) >> 16;
    return (unsigned short)r;
}

typedef __attribute__((ext_vector_type(8))) short bf16x8;
typedef __attribute__((ext_vector_type(4))) float f32x4;
typedef __attribute__((ext_vector_type(4))) _Float16 f16x4;
typedef __attribute__((ext_vector_type(8))) _Float16 f16x8;

/* per-block x-dtype detect (2KB read, LDS count) */
__device__ int detect_ff(const unsigned short* xr) {
    __shared__ int dacc;
    if (threadIdx.x == 0) dacc = 0;
    __syncthreads();
    int g = 0;
    for (int j = 0; j < 4; j++) {
        unsigned short u = xr[(threadIdx.x * 4 + j) * 2];
        int e = (u >> 7) & 0xFF;
        if (u == 0 || u == 0x8000 || (e >= 100 && e <= 140)) g++;
    }
    atomicAdd(&dacc, g);
    __syncthreads();
    return dacc >= 922;
}

/* K1: zero (deg/sums/misc) + dtype detect + W->bf16 + params->fp32. */
__global__ void k_setup(int* deg, float* sums, int* misc, const unsigned short* xr,
                        const int* ei, int* flags, const void* W, const void* bias,
                        const void* gamma, const void* beta, unsigned short* Wb,
                        float* pf) {
    int b = blockIdx.x;
    int t = threadIdx.x;
    if (b < 196) {
        int i = b * 256 + t;
        if (i < NN) deg[i] = 0;
        if (i < 2 * DD) sums[i] = 0.f;
        if (i < 16) misc[i] = 0;
        return;
    }
    if (b == 196) {
        __shared__ int acc2;
        if (t == 0) acc2 = 0;
        int ff = detect_ff(xr); /* has its own syncthreads */
        if (ei[2 * t + 1] != 0) atomicAdd(&acc2, 1);
        __syncthreads();
        if (t == 0) {
            flags[0] = ff;
            flags[1] = (acc2 == 0) ? 1 : 0; /* 1 => int64 edges */
        }
        pf[t] = rdF(bias, t, ff);
        pf[DD + t] = rdF(gamma, t, ff);
        pf[2 * DD + t] = rdF(beta, t, ff);
        return;
    }
    int ff = detect_ff(xr);
    int i = (b - 197) * 256 + t;
    Wb[i] = f2b_rne(rdF(W, i, ff));
}

/* K2: degree count, reading raw edges directly (no e32 intermediate) */
__global__ void k_edges(const int* raw, const int* flags, int* deg) {
    int e = blockIdx.x * 256 + threadIdx.x;
    if (e >= NE) return;
    int f = flags[1];
    int r = f ? raw[2 * e] : raw[e];
    int c = f ? raw[2 * (NE + e)] : raw[NE + e];
    if ((unsigned int)r < NN && (unsigned int)c < NN) atomicAdd(&deg[c], 1);
}

/* K3: CSR slot allocation + dinv (block-local scan + global atomic base). */
__global__ __launch_bounds__(256) void k_alloc(const int* deg, int* off, int* cursor,
                                               float* dinv, int* gcur) {
    __shared__ int sm[256];
    __shared__ int sbase;
    int tid = threadIdx.x;
    int i = blockIdx.x * 256 + tid;
    int v = (i < NN) ? deg[i] : 0;
    sm[tid] = v;
    __syncthreads();
    for (int s = 1; s < 256; s <<= 1) {
        int t = (tid >= s) ? sm[tid - s] : 0;
        __syncthreads();
        sm[tid] += t;
        __syncthreads();
    }
    if (tid == 255) sbase = atomicAdd(gcur, sm[255]);
    __syncthreads();
    if (i < NN) {
        int o = sbase + sm[tid] - v;
        off[i] = o;
        cursor[i] = o;
        dinv[i] = rsqrtf((float)(v + 1));
    }
}

/* K4: MFMA GEMM, 128-col tiles. Block = 4 waves x 16 rows, 128 cols.
   W-tile 128x256 bf16 in LDS, 528B pitch = 67.6 KB -> 2 blocks/CU.
   h' = dinv[n] * (x @ W^T), fp32 acc, fp16 store.
   C/D: col = lane&15, row = (lane>>4)*4 + reg  (m89-verified mapping) */
#define WP 264 /* LDS row pitch in shorts (512B data + 16B pad) */
__global__ __launch_bounds__(256) void k_gemm(const void* x, const int* flags,
                                              const unsigned short* Wb,
                                              const float* dinv, _Float16* h) {
    __shared__ unsigned short wlds[128 * WP]; /* 67584 B */
    int t = threadIdx.x;
    int rt = blockIdx.x >> 1;   /* row-tile 0..781 */
    int ctile = blockIdx.x & 1; /* col-tile 0..1 (128 cols each) */

    const unsigned short* wsrc = Wb + ctile * 128 * DD;
#pragma unroll
    for (int i = 0; i < 16; i++) {
        int c = t + i * 256;
        int row = c >> 5;
        int off = (c & 31) * 8;
        bf16x8 v = *(const bf16x8*)(wsrc + row * DD + off);
        *(bf16x8*)(&wlds[row * WP + off]) = v;
    }
    __syncthreads();

    int wave = t >> 6;
    int lane = t & 63;
    int rw = rt * 4 + wave;
    if (rw >= 3125) return; /* after barrier: safe */
    int r0 = rw * 16;
    int l15 = lane & 15;
    int kq = lane >> 4;

    bf16x8 a[8];
    int ff = flags[0];
    if (ff) {
        const unsigned short* p =
            (const unsigned short*)x + (unsigned long long)(r0 + l15) * DD + kq * 8;
#pragma unroll
        for (int k = 0; k < 8; k++)
            a[k] = *(const bf16x8*)(p + k * 32);
    } else {
        const float* p = (const float*)x + (unsigned long long)(r0 + l15) * DD + kq * 8;
#pragma unroll
        for (int k = 0; k < 8; k++) {
#pragma unroll
            for (int j = 0; j < 8; j++)
                a[k][j] = (short)f2b_rne(p[k * 32 + j]);
        }
    }

    float dv[4];
#pragma unroll
    for (int j = 0; j < 4; j++) dv[j] = dinv[r0 + kq * 4 + j];

    f32x4 acc[8];
#pragma unroll
    for (int ct = 0; ct < 8; ct++) acc[ct] = (f32x4){0.f, 0.f, 0.f, 0.f};

#pragma unroll
    for (int k = 0; k < 8; k++) {
        bf16x8 bfr[8];
#pragma unroll
        for (int ct = 0; ct < 8; ct++)
            bfr[ct] = *(const bf16x8*)(&wlds[(ct * 16 + l15) * WP + kq * 8 + k * 32]);
#pragma unroll
        for (int ct = 0; ct < 8; ct++)
            acc[ct] = __builtin_amdgcn_mfma_f32_16x16x32_bf16(a[k], bfr[ct], acc[ct],
                                                              0, 0, 0);
    }

#pragma unroll
    for (int ct = 0; ct < 8; ct++) {
        _Float16* op = h + (unsigned long long)(r0 + kq * 4) * DD + ctile * 128 +
                       ct * 16 + l15;
#pragma unroll
        for (int j = 0; j < 4; j++)
            op[(unsigned long long)j * DD] = (_Float16)(acc[ct][j] * dv[j]);
    }
}

/* K5: CSR fill, reading raw edges directly. No LDS -> full occupancy. */
__global__ void k_fill(const int* raw, const int* flags, int* cursor, int* csrc) {
    int e = blockIdx.x * 256 + threadIdx.x;
    if (e >= NE) return;
    int f = flags[1];
    int r = f ? raw[2 * e] : raw[e];
    int c = f ? raw[2 * (NE + e)] : raw[NE + e];
    if ((unsigned int)c < NN && (unsigned int)r < NN) {
        int slot = atomicAdd(&cursor[c], 1);
        if ((unsigned int)slot < NE) csrc[slot] = r;
    }
}

/* K6: aggregate + bias -> fp16 agg. one node per wave, 8-deep ILP unroll. */
__global__ __launch_bounds__(256) void g_agg(const _Float16* h, const float* dinv,
                                             const int* off, const int* deg,
                                             const int* csrc, const float* pf,
                                             _Float16* agg) {
    int lane = threadIdx.x & 63;
    int n = blockIdx.x * 4 + (threadIdx.x >> 6);
    int f0 = lane * 4;
    int s = __builtin_amdgcn_readfirstlane(off[n]);
    int cnt = __builtin_amdgcn_readfirstlane(deg[n]);
    float dn = dinv[n];
    f16x4 hv = *(const f16x4*)(h + (unsigned long long)n * DD + f0);
    float a0 = (float)hv[0];
    float a1 = (float)hv[1];
    float a2 = (float)hv[2];
    float a3 = (float)hv[3];
    const int* ip = csrc + s;
    int k = 0;
    for (; k + 8 <= cnt; k += 8) {
        int i0 = ip[k + 0], i1 = ip[k + 1], i2 = ip[k + 2], i3 = ip[k + 3];
        int i4 = ip[k + 4], i5 = ip[k + 5], i6 = ip[k + 6], i7 = ip[k + 7];
        f16x4 v0 = *(const f16x4*)(h + (unsigned long long)i0 * DD + f0);
        f16x4 v1 = *(const f16x4*)(h + (unsigned long long)i1 * DD + f0);
        f16x4 v2 = *(const f16x4*)(h + (unsigned long long)i2 * DD + f0);
        f16x4 v3 = *(const f16x4*)(h + (unsigned long long)i3 * DD + f0);
        f16x4 v4 = *(const f16x4*)(h + (unsigned long long)i4 * DD + f0);
        f16x4 v5 = *(const f16x4*)(h + (unsigned long long)i5 * DD + f0);
        f16x4 v6 = *(const f16x4*)(h + (unsigned long long)i6 * DD + f0);
        f16x4 v7 = *(const f16x4*)(h + (unsigned long long)i7 * DD + f0);
        a0 += (((float)v0[0] + (float)v1[0]) + ((float)v2[0] + (float)v3[0])) +
              (((float)v4[0] + (float)v5[0]) + ((float)v6[0] + (float)v7[0]));
        a1 += (((float)v0[1] + (float)v1[1]) + ((float)v2[1] + (float)v3[1])) +
              (((float)v4[1] + (float)v5[1]) + ((float)v6[1] + (float)v7[1]));
        a2 += (((float)v0[2] + (float)v1[2]) + ((float)v2[2] + (float)v3[2])) +
              (((float)v4[2] + (float)v5[2]) + ((float)v6[2] + (float)v7[2]));
        a3 += (((float)v0[3] + (float)v1[3]) + ((float)v2[3] + (float)v3[3])) +
              (((float)v4[3] + (float)v5[3]) + ((float)v6[3] + (float)v7[3]));
    }
    for (; k + 4 <= cnt; k += 4) {
        int i0 = ip[k + 0], i1 = ip[k + 1], i2 = ip[k + 2], i3 = ip[k + 3];
        f16x4 v0 = *(const f16x4*)(h + (unsigned long long)i0 * DD + f0);
        f16x4 v1 = *(const f16x4*)(h + (unsigned long long)i1 * DD + f0);
        f16x4 v2 = *(const f16x4*)(h + (unsigned long long)i2 * DD + f0);
        f16x4 v3 = *(const f16x4*)(h + (unsigned long long)i3 * DD + f0);
        a0 += ((float)v0[0] + (float)v1[0]) + ((float)v2[0] + (float)v3[0]);
        a1 += ((float)v0[1] + (float)v1[1]) + ((float)v2[1] + (float)v3[1]);
        a2 += ((float)v0[2] + (float)v1[2]) + ((float)v2[2] + (float)v3[2]);
        a3 += ((float)v0[3] + (float)v1[3]) + ((float)v2[3] + (float)v3[3]);
    }
    for (; k < cnt; k++) {
        int i0 = ip[k];
        f16x4 v0 = *(const f16x4*)(h + (unsigned long long)i0 * DD + f0);
        a0 += (float)v0[0];
        a1 += (float)v0[1];
        a2 += (float)v0[2];
        a3 += (float)v0[3];
    }
    f16x4 o;
    o[0] = (_Float16)(dn * a0 + pf[f0 + 0]);
    o[1] = (_Float16)(dn * a1 + pf[f0 + 1]);
    o[2] = (_Float16)(dn * a2 + pf[f0 + 2]);
    o[3] = (_Float16)(dn * a3 + pf[f0 + 3]);
    *(f16x4*)(agg + (unsigned long long)n * DD + f0) = o;
}

/* K7: stats + fin fused. R22 rewrite of the 67us strided-scalar version:
   782 blocks x 64 rows; thread (rg,cg) reads f16x8 (coalesced: one wave
   covers two full 512B rows per instr), 8 reg partials, LDS reduce,
   512 global atomics/block. Fin via threadfence+ticket (done==781). */
__global__ __launch_bounds__(256) void k_stats(const _Float16* agg, float* sums,
                                               const float* pf, float* ss, int* done) {
    __shared__ float ls[2][DD];
    int t = threadIdx.x;
    int rg = t >> 5;  /* row group 0..7 */
    int cg = t & 31;  /* feature octet 0..31 */
    float s[8], s2[8];
#pragma unroll
    for (int j = 0; j < 8; j++) { s[j] = 0.f; s2[j] = 0.f; }
    int row0 = blockIdx.x * 64;
    int rend = row0 + 64;
    if (rend > NN) rend = NN;
    for (int r = row0 + rg; r < rend; r += 8) {
        f16x8 v = *(const f16x8*)(agg + (unsigned long long)r * DD + cg * 8);
#pragma unroll
        for (int j = 0; j < 8; j++) {
            float f = (float)v[j];
            s[j] += f;
            s2[j] += f * f;
        }
    }
    ls[0][t] = 0.f;
    ls[1][t] = 0.f;
    __syncthreads();
#pragma unroll
    for (int j = 0; j < 8; j++) {
        atomicAdd(&ls[0][cg * 8 + j], s[j]);
        atomicAdd(&ls[1][cg * 8 + j], s2[j]);
    }
    __syncthreads();
    atomicAdd(&sums[t], ls[0][t]);
    atomicAdd(&sums[DD + t], ls[1][t]);
    __threadfence();
    __syncthreads();
    __shared__ int lastf;
    if (t == 0) lastf = (atomicAdd(done, 1) == 781) ? 1 : 0;
    __syncthreads();
    if (lastf) {
        float sv = __hip_atomic_load(&sums[t], __ATOMIC_RELAXED,
                                     __HIP_MEMORY_SCOPE_AGENT);
        float sv2 = __hip_atomic_load(&sums[DD + t], __ATOMIC_RELAXED,
                                      __HIP_MEMORY_SCOPE_AGENT);
        float mean = sv * (1.0f / NN);
        float var = fmaxf(sv2 * (1.0f / NN) - mean * mean, 0.f);
        float sc = pf[DD + t] * rsqrtf(var + 1e-5f);
        ss[t] = sc;
        ss[DD + t] = pf[2 * DD + t] - mean * sc;
    }
}

/* K8: BN + ReLU: fp16 agg -> fp32 out. 8 elems/thread, grid 6250. */
__global__ void DenseGCNLayer_2937757631000_kernel(const _Float16* agg, const float* ss,
                                                   float* out) {
    int t = threadIdx.x;
    unsigned long long base =
        (unsigned long long)blockIdx.x * 2048 + (unsigned int)t * 8;
    int f = (int)(base & 255);
    f16x8 v = *(const f16x8*)(agg + base);
    f32x4 o0, o1;
#pragma unroll
    for (int j = 0; j < 4; j++)
        o0[j] = fmaxf(ss[f + j] * (float)v[j] + ss[DD + f + j], 0.f);
#pragma unroll
    for (int j = 0; j < 4; j++)
        o1[j] = fmaxf(ss[f + 4 + j] * (float)v[4 + j] + ss[DD + f + 4 + j], 0.f);
    *(f32x4*)(out + base) = o0;
    *(f32x4*)(out + base + 4) = o1;
}

extern "C" void kernel_launch(void* const* d_in, const int* in_sizes, int n_in,
                              void* d_out, int out_size, void* d_ws, size_t ws_size,
                              hipStream_t stream) {
    const void* x = d_in[0];
    const int* ei = (const int*)d_in[1];
    const void* W = d_in[2];
    const void* bias = d_in[3];
    const void* gamma = d_in[4];
    const void* beta = d_in[5];
    char* ws = (char*)d_ws;
    float* out = (float*)d_out;

    _Float16* h = (_Float16*)(ws + 0UL);          /* 25.6 MB fp16 */
    _Float16* agg = (_Float16*)(ws + 51200000UL); /* 25.6 MB fp16 */
    int* csrc = (int*)(ws + 108800000UL);         /* 3.2 MB */
    unsigned short* Wb = (unsigned short*)(ws + 112000000UL); /* 128 KB bf16 */
    int* deg = (int*)(ws + 112262144UL);
    float* dinv = (float*)(ws + 112462336UL);
    int* off = (int*)(ws + 112662528UL);
    int* cursor = (int*)(ws + 112862720UL);
    int* misc = (int*)(ws + 113063936UL); /* gcur, done, ... (16 ints) */
    float* pf = (float*)(ws + 113064960UL);
    float* sums = (float*)(ws + 113068032UL);
    float* ss = (float*)(ws + 113070080UL);
    int* flags = (int*)(ws + 113072128UL);

    if (ws_size < WS_NEED) {
        fprintf(stderr, "R22_WS_SMALL %zu\n", ws_size);
        fflush(stderr);
        return;
    }

    k_setup<<<453, 256, 0, stream>>>(deg, sums, misc, (const unsigned short*)x, ei,
                                     flags, W, bias, gamma, beta, Wb, pf);
    k_edges<<<3125, 256, 0, stream>>>(ei, flags, deg);
    k_alloc<<<196, 256, 0, stream>>>(deg, off, cursor, dinv, &misc[0]);
    k_gemm<<<1564, 256, 0, stream>>>(x, flags, Wb, dinv, h);
    k_fill<<<3125, 256, 0, stream>>>(ei, flags, cursor, csrc);
    g_agg<<<12500, 256, 0, stream>>>(h, dinv, off, deg, csrc, pf, agg);
    k_stats<<<782, 256, 0, stream>>>(agg, sums, pf, ss, &misc[1]);
    DenseGCNLayer_2937757631000_kernel<<<6250, 256, 0, stream>>>(agg, ss, out);
}

// Round 11
// 327.561 us; speedup vs baseline: 1.1194x; 1.0432x over previous
//
#include <hip/hip_runtime.h>
#include <cstdio>

#define NN 50000
#define NE 800000
#define DD 256
#define WS_NEED 113080000UL

__attribute__((constructor)) static void r23_on_load(void) {
    fprintf(stderr, "R23SO_LOADED\n");
    fflush(stderr);
}

__device__ float b2f(unsigned short u) {
    union { unsigned int i; float f; } c;
    c.i = ((unsigned int)u) << 16;
    return c.f;
}
__device__ float clampf(float v) { return fminf(fmaxf(v, -65504.f), 65504.f); }
__device__ float rdF(const void* p, long long idx, int ff) {
    if (ff) return clampf(b2f(((const unsigned short*)p)[idx]));
    return clampf(((const float*)p)[idx]);
}
__device__ unsigned short f2b_rne(float f) {
    union { float f; unsigned int u; } c;
    c.f = f;
    unsigned int r = (c.u + 0x7FFFu + ((c.u >> 16) & 1u)) >> 16;
    return (unsigned short)r;
}

typedef __attribute__((ext_vector_type(8))) short bf16x8;
typedef __attribute__((ext_vector_type(4))) float f32x4;
typedef __attribute__((ext_vector_type(4))) _Float16 f16x4;
typedef __attribute__((ext_vector_type(8))) _Float16 f16x8;

/* per-block x-dtype detect (2KB read, LDS count) */
__device__ int detect_ff(const unsigned short* xr) {
    __shared__ int dacc;
    if (threadIdx.x == 0) dacc = 0;
    __syncthreads();
    int g = 0;
    for (int j = 0; j < 4; j++) {
        unsigned short u = xr[(threadIdx.x * 4 + j) * 2];
        int e = (u >> 7) & 0xFF;
        if (u == 0 || u == 0x8000 || (e >= 100 && e <= 140)) g++;
    }
    atomicAdd(&dacc, g);
    __syncthreads();
    return dacc >= 922;
}

/* K1: zero (deg/misc) + dtype detect + W->bf16 + params->fp32. */
__global__ void k_setup(int* deg, int* misc, const unsigned short* xr,
                        const int* ei, int* flags, const void* W, const void* bias,
                        const void* gamma, const void* beta, unsigned short* Wb,
                        float* pf) {
    int b = blockIdx.x;
    int t = threadIdx.x;
    if (b < 196) {
        int i = b * 256 + t;
        if (i < NN) deg[i] = 0;
        if (i < 16) misc[i] = 0;
        return;
    }
    if (b == 196) {
        __shared__ int acc2;
        if (t == 0) acc2 = 0;
        int ff = detect_ff(xr); /* has its own syncthreads */
        if (ei[2 * t + 1] != 0) atomicAdd(&acc2, 1);
        __syncthreads();
        if (t == 0) {
            flags[0] = ff;
            flags[1] = (acc2 == 0) ? 1 : 0; /* 1 => int64 edges */
        }
        pf[t] = rdF(bias, t, ff);
        pf[DD + t] = rdF(gamma, t, ff);
        pf[2 * DD + t] = rdF(beta, t, ff);
        return;
    }
    int ff = detect_ff(xr);
    int i = (b - 197) * 256 + t;
    Wb[i] = f2b_rne(rdF(W, i, ff));
}

/* K2: degree count, reading raw edges directly */
__global__ void k_edges(const int* raw, const int* flags, int* deg) {
    int e = blockIdx.x * 256 + threadIdx.x;
    if (e >= NE) return;
    int f = flags[1];
    int r = f ? raw[2 * e] : raw[e];
    int c = f ? raw[2 * (NE + e)] : raw[NE + e];
    if ((unsigned int)r < NN && (unsigned int)c < NN) atomicAdd(&deg[c], 1);
}

/* K3: CSR slot allocation + dinv (block-local scan + global atomic base). */
__global__ __launch_bounds__(256) void k_alloc(const int* deg, int* off, int* cursor,
                                               float* dinv, int* gcur) {
    __shared__ int sm[256];
    __shared__ int sbase;
    int tid = threadIdx.x;
    int i = blockIdx.x * 256 + tid;
    int v = (i < NN) ? deg[i] : 0;
    sm[tid] = v;
    __syncthreads();
    for (int s = 1; s < 256; s <<= 1) {
        int t = (tid >= s) ? sm[tid - s] : 0;
        __syncthreads();
        sm[tid] += t;
        __syncthreads();
    }
    if (tid == 255) sbase = atomicAdd(gcur, sm[255]);
    __syncthreads();
    if (i < NN) {
        int o = sbase + sm[tid] - v;
        off[i] = o;
        cursor[i] = o;
        dinv[i] = rsqrtf((float)(v + 1));
    }
}

/* K4: MFMA GEMM, 128-col tiles. Block = 4 waves x 16 rows, 128 cols.
   W-tile 128x256 bf16 in LDS, 528B pitch = 67.6 KB -> 2 blocks/CU.
   h' = dinv[n] * (x @ W^T), fp32 acc, fp16 store.
   C/D: col = lane&15, row = (lane>>4)*4 + reg  (m89-verified mapping) */
#define WP 264 /* LDS row pitch in shorts (512B data + 16B pad) */
__global__ __launch_bounds__(256) void k_gemm(const void* x, const int* flags,
                                              const unsigned short* Wb,
                                              const float* dinv, _Float16* h) {
    __shared__ unsigned short wlds[128 * WP]; /* 67584 B */
    int t = threadIdx.x;
    int rt = blockIdx.x >> 1;   /* row-tile 0..781 */
    int ctile = blockIdx.x & 1; /* col-tile 0..1 (128 cols each) */

    const unsigned short* wsrc = Wb + ctile * 128 * DD;
#pragma unroll
    for (int i = 0; i < 16; i++) {
        int c = t + i * 256;
        int row = c >> 5;
        int off = (c & 31) * 8;
        bf16x8 v = *(const bf16x8*)(wsrc + row * DD + off);
        *(bf16x8*)(&wlds[row * WP + off]) = v;
    }
    __syncthreads();

    int wave = t >> 6;
    int lane = t & 63;
    int rw = rt * 4 + wave;
    if (rw >= 3125) return; /* after barrier: safe */
    int r0 = rw * 16;
    int l15 = lane & 15;
    int kq = lane >> 4;

    bf16x8 a[8];
    int ff = flags[0];
    if (ff) {
        const unsigned short* p =
            (const unsigned short*)x + (unsigned long long)(r0 + l15) * DD + kq * 8;
#pragma unroll
        for (int k = 0; k < 8; k++)
            a[k] = *(const bf16x8*)(p + k * 32);
    } else {
        const float* p = (const float*)x + (unsigned long long)(r0 + l15) * DD + kq * 8;
#pragma unroll
        for (int k = 0; k < 8; k++) {
#pragma unroll
            for (int j = 0; j < 8; j++)
                a[k][j] = (short)f2b_rne(p[k * 32 + j]);
        }
    }

    float dv[4];
#pragma unroll
    for (int j = 0; j < 4; j++) dv[j] = dinv[r0 + kq * 4 + j];

    f32x4 acc[8];
#pragma unroll
    for (int ct = 0; ct < 8; ct++) acc[ct] = (f32x4){0.f, 0.f, 0.f, 0.f};

#pragma unroll
    for (int k = 0; k < 8; k++) {
        bf16x8 bfr[8];
#pragma unroll
        for (int ct = 0; ct < 8; ct++)
            bfr[ct] = *(const bf16x8*)(&wlds[(ct * 16 + l15) * WP + kq * 8 + k * 32]);
#pragma unroll
        for (int ct = 0; ct < 8; ct++)
            acc[ct] = __builtin_amdgcn_mfma_f32_16x16x32_bf16(a[k], bfr[ct], acc[ct],
                                                              0, 0, 0);
    }

#pragma unroll
    for (int ct = 0; ct < 8; ct++) {
        _Float16* op = h + (unsigned long long)(r0 + kq * 4) * DD + ctile * 128 +
                       ct * 16 + l15;
#pragma unroll
        for (int j = 0; j < 4; j++)
            op[(unsigned long long)j * DD] = (_Float16)(acc[ct][j] * dv[j]);
    }
}

/* K5: CSR fill, reading raw edges directly. No LDS -> full occupancy. */
__global__ void k_fill(const int* raw, const int* flags, int* cursor, int* csrc) {
    int e = blockIdx.x * 256 + threadIdx.x;
    if (e >= NE) return;
    int f = flags[1];
    int r = f ? raw[2 * e] : raw[e];
    int c = f ? raw[2 * (NE + e)] : raw[NE + e];
    if ((unsigned int)c < NN && (unsigned int)r < NN) {
        int slot = atomicAdd(&cursor[c], 1);
        if ((unsigned int)slot < NE) csrc[slot] = r;
    }
}

/* K6: aggregate + bias -> fp16 agg. one node per wave, 8-deep ILP unroll. */
__global__ __launch_bounds__(256) void g_agg(const _Float16* h, const float* dinv,
                                             const int* off, const int* deg,
                                             const int* csrc, const float* pf,
                                             _Float16* agg) {
    int lane = threadIdx.x & 63;
    int n = blockIdx.x * 4 + (threadIdx.x >> 6);
    int f0 = lane * 4;
    int s = __builtin_amdgcn_readfirstlane(off[n]);
    int cnt = __builtin_amdgcn_readfirstlane(deg[n]);
    float dn = dinv[n];
    f16x4 hv = *(const f16x4*)(h + (unsigned long long)n * DD + f0);
    float a0 = (float)hv[0];
    float a1 = (float)hv[1];
    float a2 = (float)hv[2];
    float a3 = (float)hv[3];
    const int* ip = csrc + s;
    int k = 0;
    for (; k + 8 <= cnt; k += 8) {
        int i0 = ip[k + 0], i1 = ip[k + 1], i2 = ip[k + 2], i3 = ip[k + 3];
        int i4 = ip[k + 4], i5 = ip[k + 5], i6 = ip[k + 6], i7 = ip[k + 7];
        f16x4 v0 = *(const f16x4*)(h + (unsigned long long)i0 * DD + f0);
        f16x4 v1 = *(const f16x4*)(h + (unsigned long long)i1 * DD + f0);
        f16x4 v2 = *(const f16x4*)(h + (unsigned long long)i2 * DD + f0);
        f16x4 v3 = *(const f16x4*)(h + (unsigned long long)i3 * DD + f0);
        f16x4 v4 = *(const f16x4*)(h + (unsigned long long)i4 * DD + f0);
        f16x4 v5 = *(const f16x4*)(h + (unsigned long long)i5 * DD + f0);
        f16x4 v6 = *(const f16x4*)(h + (unsigned long long)i6 * DD + f0);
        f16x4 v7 = *(const f16x4*)(h + (unsigned long long)i7 * DD + f0);
        a0 += (((float)v0[0] + (float)v1[0]) + ((float)v2[0] + (float)v3[0])) +
              (((float)v4[0] + (float)v5[0]) + ((float)v6[0] + (float)v7[0]));
        a1 += (((float)v0[1] + (float)v1[1]) + ((float)v2[1] + (float)v3[1])) +
              (((float)v4[1] + (float)v5[1]) + ((float)v6[1] + (float)v7[1]));
        a2 += (((float)v0[2] + (float)v1[2]) + ((float)v2[2] + (float)v3[2])) +
              (((float)v4[2] + (float)v5[2]) + ((float)v6[2] + (float)v7[2]));
        a3 += (((float)v0[3] + (float)v1[3]) + ((float)v2[3] + (float)v3[3])) +
              (((float)v4[3] + (float)v5[3]) + ((float)v6[3] + (float)v7[3]));
    }
    for (; k + 4 <= cnt; k += 4) {
        int i0 = ip[k + 0], i1 = ip[k + 1], i2 = ip[k + 2], i3 = ip[k + 3];
        f16x4 v0 = *(const f16x4*)(h + (unsigned long long)i0 * DD + f0);
        f16x4 v1 = *(const f16x4*)(h + (unsigned long long)i1 * DD + f0);
        f16x4 v2 = *(const f16x4*)(h + (unsigned long long)i2 * DD + f0);
        f16x4 v3 = *(const f16x4*)(h + (unsigned long long)i3 * DD + f0);
        a0 += ((float)v0[0] + (float)v1[0]) + ((float)v2[0] + (float)v3[0]);
        a1 += ((float)v0[1] + (float)v1[1]) + ((float)v2[1] + (float)v3[1]);
        a2 += ((float)v0[2] + (float)v1[2]) + ((float)v2[2] + (float)v3[2]);
        a3 += ((float)v0[3] + (float)v1[3]) + ((float)v2[3] + (float)v3[3]);
    }
    for (; k < cnt; k++) {
        int i0 = ip[k];
        f16x4 v0 = *(const f16x4*)(h + (unsigned long long)i0 * DD + f0);
        a0 += (float)v0[0];
        a1 += (float)v0[1];
        a2 += (float)v0[2];
        a3 += (float)v0[3];
    }
    f16x4 o;
    o[0] = (_Float16)(dn * a0 + pf[f0 + 0]);
    o[1] = (_Float16)(dn * a1 + pf[f0 + 1]);
    o[2] = (_Float16)(dn * a2 + pf[f0 + 2]);
    o[3] = (_Float16)(dn * a3 + pf[f0 + 3]);
    *(f16x4*)(agg + (unsigned long long)n * DD + f0) = o;
}

/* K7a: per-block partial stats, NO global atomics / fence / ticket.
   (R23: R22's fence+atomic tail was the 59us cost — WRITE_SIZE 1.6MB of
   forced L2 writebacks. Plain partial stores + stream-order visibility.)
   782 blocks x 64 rows; coalesced f16x8 reads; LDS reduce; 2KB partials. */
__global__ __launch_bounds__(256) void k_stats1(const _Float16* agg, float* pstat) {
    __shared__ float ls[2][DD];
    int t = threadIdx.x;
    int rg = t >> 5;  /* row group 0..7 */
    int cg = t & 31;  /* feature octet 0..31 */
    float s[8], s2[8];
#pragma unroll
    for (int j = 0; j < 8; j++) { s[j] = 0.f; s2[j] = 0.f; }
    int row0 = blockIdx.x * 64;
    int rend = row0 + 64;
    if (rend > NN) rend = NN;
    for (int r = row0 + rg; r < rend; r += 8) {
        f16x8 v = *(const f16x8*)(agg + (unsigned long long)r * DD + cg * 8);
#pragma unroll
        for (int j = 0; j < 8; j++) {
            float f = (float)v[j];
            s[j] += f;
            s2[j] += f * f;
        }
    }
    ls[0][t] = 0.f;
    ls[1][t] = 0.f;
    __syncthreads();
#pragma unroll
    for (int j = 0; j < 8; j++) {
        atomicAdd(&ls[0][cg * 8 + j], s[j]);
        atomicAdd(&ls[1][cg * 8 + j], s2[j]);
    }
    __syncthreads();
    float* pb = pstat + (unsigned long long)blockIdx.x * 512;
    pb[t] = ls[0][t];
    pb[256 + t] = ls[1][t];
}

/* K7b: final reduce over 782 partials + fin. 32 blocks; block j owns
   features j*8..j*8+7 (sum slots j*8+c, sumsq slots 256+j*8+c).
   Thread (r = t>>4, c = t&15): c<8 -> sum slot, c>=8 -> sumsq slot. */
__global__ __launch_bounds__(256) void k_stats2(const float* pstat, const float* pf,
                                                float* ss) {
    __shared__ float ls[16][16];
    int t = threadIdx.x;
    int r = t >> 4;
    int c = t & 15;
    int j = blockIdx.x;
    int slot = (c < 8) ? (j * 8 + c) : (256 + j * 8 + (c - 8));
    float acc = 0.f;
    for (int b = r; b < 782; b += 16)
        acc += pstat[(unsigned long long)b * 512 + slot];
    ls[r][c] = acc;
    __syncthreads();
    for (int step = 8; step >= 1; step >>= 1) {
        if (r < step) ls[r][c] += ls[r + step][c];
        __syncthreads();
    }
    if (t < 8) {
        int f = j * 8 + t;
        float sv = ls[0][t];
        float sv2 = ls[0][t + 8];
        float mean = sv * (1.0f / NN);
        float var = fmaxf(sv2 * (1.0f / NN) - mean * mean, 0.f);
        float sc = pf[DD + f] * rsqrtf(var + 1e-5f);
        ss[f] = sc;
        ss[DD + f] = pf[2 * DD + f] - mean * sc;
    }
}

/* K8: BN + ReLU: fp16 agg -> fp32 out. 8 elems/thread, grid 6250. */
__global__ void DenseGCNLayer_2937757631000_kernel(const _Float16* agg, const float* ss,
                                                   float* out) {
    int t = threadIdx.x;
    unsigned long long base =
        (unsigned long long)blockIdx.x * 2048 + (unsigned int)t * 8;
    int f = (int)(base & 255);
    f16x8 v = *(const f16x8*)(agg + base);
    f32x4 o0, o1;
#pragma unroll
    for (int j = 0; j < 4; j++)
        o0[j] = fmaxf(ss[f + j] * (float)v[j] + ss[DD + f + j], 0.f);
#pragma unroll
    for (int j = 0; j < 4; j++)
        o1[j] = fmaxf(ss[f + 4 + j] * (float)v[4 + j] + ss[DD + f + 4 + j], 0.f);
    *(f32x4*)(out + base) = o0;
    *(f32x4*)(out + base + 4) = o1;
}

extern "C" void kernel_launch(void* const* d_in, const int* in_sizes, int n_in,
                              void* d_out, int out_size, void* d_ws, size_t ws_size,
                              hipStream_t stream) {
    const void* x = d_in[0];
    const int* ei = (const int*)d_in[1];
    const void* W = d_in[2];
    const void* bias = d_in[3];
    const void* gamma = d_in[4];
    const void* beta = d_in[5];
    char* ws = (char*)d_ws;
    float* out = (float*)d_out;

    _Float16* h = (_Float16*)(ws + 0UL);          /* 25.6 MB fp16 */
    _Float16* agg = (_Float16*)(ws + 51200000UL); /* 25.6 MB fp16 */
    float* pstat = (float*)(ws + 102400000UL);    /* 1.6 MB partial stats */
    int* csrc = (int*)(ws + 108800000UL);         /* 3.2 MB */
    unsigned short* Wb = (unsigned short*)(ws + 112000000UL); /* 128 KB bf16 */
    int* deg = (int*)(ws + 112262144UL);
    float* dinv = (float*)(ws + 112462336UL);
    int* off = (int*)(ws + 112662528UL);
    int* cursor = (int*)(ws + 112862720UL);
    int* misc = (int*)(ws + 113063936UL); /* gcur, ... (16 ints) */
    float* pf = (float*)(ws + 113064960UL);
    float* ss = (float*)(ws + 113070080UL);
    int* flags = (int*)(ws + 113072128UL);

    if (ws_size < WS_NEED) {
        fprintf(stderr, "R23_WS_SMALL %zu\n", ws_size);
        fflush(stderr);
        return;
    }

    k_setup<<<453, 256, 0, stream>>>(deg, misc, (const unsigned short*)x, ei,
                                     flags, W, bias, gamma, beta, Wb, pf);
    k_edges<<<3125, 256, 0, stream>>>(ei, flags, deg);
    k_alloc<<<196, 256, 0, stream>>>(deg, off, cursor, dinv, &misc[0]);
    k_gemm<<<1564, 256, 0, stream>>>(x, flags, Wb, dinv, h);
    k_fill<<<3125, 256, 0, stream>>>(ei, flags, cursor, csrc);
    g_agg<<<12500, 256, 0, stream>>>(h, dinv, off, deg, csrc, pf, agg);
    k_stats1<<<782, 256, 0, stream>>>(agg, pstat);
    k_stats2<<<32, 256, 0, stream>>>(pstat, pf, ss);
    DenseGCNLayer_2937757631000_kernel<<<6250, 256, 0, stream>>>(agg, ss, out);
}

// Round 12
// 322.200 us; speedup vs baseline: 1.1380x; 1.0166x over previous
//
#include <hip/hip_runtime.h>
#include <cstdio>

#define NN 50000
#define NE 800000
#define DD 256
#define WS_NEED 113080000UL

__attribute__((constructor)) static void r24_on_load(void) {
    fprintf(stderr, "R24SO_LOADED\n");
    fflush(stderr);
}

__device__ float b2f(unsigned short u) {
    union { unsigned int i; float f; } c;
    c.i = ((unsigned int)u) << 16;
    return c.f;
}
__device__ float clampf(float v) { return fminf(fmaxf(v, -65504.f), 65504.f); }
__device__ float rdF(const void* p, long long idx, int ff) {
    if (ff) return clampf(b2f(((const unsigned short*)p)[idx]));
    return clampf(((const float*)p)[idx]);
}
__device__ unsigned short f2b_rne(float f) {
    union { float f; unsigned int u; } c;
    c.f = f;
    unsigned int r = (c.u + 0x7FFFu + ((c.u >> 16) & 1u)) >> 16;
    return (unsigned short)r;
}

typedef __attribute__((ext_vector_type(8))) short bf16x8;
typedef __attribute__((ext_vector_type(4))) float f32x4;
typedef __attribute__((ext_vector_type(4))) _Float16 f16x4;
typedef __attribute__((ext_vector_type(8))) _Float16 f16x8;

/* per-block x-dtype detect (2KB read, LDS count) */
__device__ int detect_ff(const unsigned short* xr) {
    __shared__ int dacc;
    if (threadIdx.x == 0) dacc = 0;
    __syncthreads();
    int g = 0;
    for (int j = 0; j < 4; j++) {
        unsigned short u = xr[(threadIdx.x * 4 + j) * 2];
        int e = (u >> 7) & 0xFF;
        if (u == 0 || u == 0x8000 || (e >= 100 && e <= 140)) g++;
    }
    atomicAdd(&dacc, g);
    __syncthreads();
    return dacc >= 922;
}

/* K1: zero (deg/misc) + dtype detect + W->bf16 + params->fp32. */
__global__ void k_setup(int* deg, int* misc, const unsigned short* xr,
                        const int* ei, int* flags, const void* W, const void* bias,
                        const void* gamma, const void* beta, unsigned short* Wb,
                        float* pf) {
    int b = blockIdx.x;
    int t = threadIdx.x;
    if (b < 196) {
        int i = b * 256 + t;
        if (i < NN) deg[i] = 0;
        if (i < 16) misc[i] = 0;
        return;
    }
    if (b == 196) {
        __shared__ int acc2;
        if (t == 0) acc2 = 0;
        int ff = detect_ff(xr); /* has its own syncthreads */
        if (ei[2 * t + 1] != 0) atomicAdd(&acc2, 1);
        __syncthreads();
        if (t == 0) {
            flags[0] = ff;
            flags[1] = (acc2 == 0) ? 1 : 0; /* 1 => int64 edges */
        }
        pf[t] = rdF(bias, t, ff);
        pf[DD + t] = rdF(gamma, t, ff);
        pf[2 * DD + t] = rdF(beta, t, ff);
        return;
    }
    int ff = detect_ff(xr);
    int i = (b - 197) * 256 + t;
    Wb[i] = f2b_rne(rdF(W, i, ff));
}

/* K2: degree count, reading raw edges directly */
__global__ void k_edges(const int* raw, const int* flags, int* deg) {
    int e = blockIdx.x * 256 + threadIdx.x;
    if (e >= NE) return;
    int f = flags[1];
    int r = f ? raw[2 * e] : raw[e];
    int c = f ? raw[2 * (NE + e)] : raw[NE + e];
    if ((unsigned int)r < NN && (unsigned int)c < NN) atomicAdd(&deg[c], 1);
}

/* K3: CSR slot allocation + dinv (block-local scan + global atomic base). */
__global__ __launch_bounds__(256) void k_alloc(const int* deg, int* off, int* cursor,
                                               float* dinv, int* gcur) {
    __shared__ int sm[256];
    __shared__ int sbase;
    int tid = threadIdx.x;
    int i = blockIdx.x * 256 + tid;
    int v = (i < NN) ? deg[i] : 0;
    sm[tid] = v;
    __syncthreads();
    for (int s = 1; s < 256; s <<= 1) {
        int t = (tid >= s) ? sm[tid - s] : 0;
        __syncthreads();
        sm[tid] += t;
        __syncthreads();
    }
    if (tid == 255) sbase = atomicAdd(gcur, sm[255]);
    __syncthreads();
    if (i < NN) {
        int o = sbase + sm[tid] - v;
        off[i] = o;
        cursor[i] = o;
        dinv[i] = rsqrtf((float)(v + 1));
    }
}

/* K4: MFMA GEMM, FULL-W LDS (R24). Block = 1024 thr = 16 waves x 16 rows
   = 256 rows; ALL 256 cols. W (256x256 bf16) staged once per block into
   132 KB LDS (528B pitch, measured-0-conflict layout). Grid 196 = 1
   block/CU, single round, x read ONCE (was 2x with 128-col tiles).
   h' = dinv[n] * (x @ W^T), fp32 acc, fp16 store.
   C/D: col = lane&15, row = (lane>>4)*4 + reg  (m89-verified mapping) */
#define WP 264 /* LDS row pitch in shorts (512B data + 16B pad) */
__global__ __launch_bounds__(1024) void k_gemm(const void* x, const int* flags,
                                               const unsigned short* Wb,
                                               const float* dinv, _Float16* h) {
    __shared__ unsigned short wlds[256 * WP]; /* 135168 B */
    int t = threadIdx.x;

    /* stage: 256 rows x 32 chunks = 8192 16B-chunks; 1024 thr x 8 iters */
#pragma unroll
    for (int i = 0; i < 8; i++) {
        int c = t + i * 1024;
        int row = c >> 5;
        int off = (c & 31) * 8;
        bf16x8 v = *(const bf16x8*)(Wb + row * DD + off);
        *(bf16x8*)(&wlds[row * WP + off]) = v;
    }
    __syncthreads();

    int wave = t >> 6;
    int lane = t & 63;
    int rw = blockIdx.x * 16 + wave;
    if (rw >= 3125) return; /* after barrier: safe */
    int r0 = rw * 16;
    int l15 = lane & 15;
    int kq = lane >> 4;

    bf16x8 a[8];
    int ff = flags[0];
    if (ff) {
        const unsigned short* p =
            (const unsigned short*)x + (unsigned long long)(r0 + l15) * DD + kq * 8;
#pragma unroll
        for (int k = 0; k < 8; k++)
            a[k] = *(const bf16x8*)(p + k * 32);
    } else {
        const float* p = (const float*)x + (unsigned long long)(r0 + l15) * DD + kq * 8;
#pragma unroll
        for (int k = 0; k < 8; k++) {
#pragma unroll
            for (int j = 0; j < 8; j++)
                a[k][j] = (short)f2b_rne(p[k * 32 + j]);
        }
    }

    float dv[4];
#pragma unroll
    for (int j = 0; j < 4; j++) dv[j] = dinv[r0 + kq * 4 + j];

    /* ct-outer / k-inner: same per-output accumulation order as R21/R23 */
#pragma unroll
    for (int ct = 0; ct < 16; ct++) {
        f32x4 acc = {0.f, 0.f, 0.f, 0.f};
#pragma unroll
        for (int k = 0; k < 8; k++) {
            bf16x8 b = *(const bf16x8*)(&wlds[(ct * 16 + l15) * WP + kq * 8 + k * 32]);
            acc = __builtin_amdgcn_mfma_f32_16x16x32_bf16(a[k], b, acc, 0, 0, 0);
        }
        _Float16* op = h + (unsigned long long)(r0 + kq * 4) * DD + ct * 16 + l15;
#pragma unroll
        for (int j = 0; j < 4; j++)
            op[(unsigned long long)j * DD] = (_Float16)(acc[j] * dv[j]);
    }
}

/* K5: CSR fill, reading raw edges directly. No LDS -> full occupancy. */
__global__ void k_fill(const int* raw, const int* flags, int* cursor, int* csrc) {
    int e = blockIdx.x * 256 + threadIdx.x;
    if (e >= NE) return;
    int f = flags[1];
    int r = f ? raw[2 * e] : raw[e];
    int c = f ? raw[2 * (NE + e)] : raw[NE + e];
    if ((unsigned int)c < NN && (unsigned int)r < NN) {
        int slot = atomicAdd(&cursor[c], 1);
        if ((unsigned int)slot < NE) csrc[slot] = r;
    }
}

/* K6: aggregate + bias -> fp16 agg. one node per wave, 8-deep ILP unroll. */
__global__ __launch_bounds__(256) void g_agg(const _Float16* h, const float* dinv,
                                             const int* off, const int* deg,
                                             const int* csrc, const float* pf,
                                             _Float16* agg) {
    int lane = threadIdx.x & 63;
    int n = blockIdx.x * 4 + (threadIdx.x >> 6);
    int f0 = lane * 4;
    int s = __builtin_amdgcn_readfirstlane(off[n]);
    int cnt = __builtin_amdgcn_readfirstlane(deg[n]);
    float dn = dinv[n];
    f16x4 hv = *(const f16x4*)(h + (unsigned long long)n * DD + f0);
    float a0 = (float)hv[0];
    float a1 = (float)hv[1];
    float a2 = (float)hv[2];
    float a3 = (float)hv[3];
    const int* ip = csrc + s;
    int k = 0;
    for (; k + 8 <= cnt; k += 8) {
        int i0 = ip[k + 0], i1 = ip[k + 1], i2 = ip[k + 2], i3 = ip[k + 3];
        int i4 = ip[k + 4], i5 = ip[k + 5], i6 = ip[k + 6], i7 = ip[k + 7];
        f16x4 v0 = *(const f16x4*)(h + (unsigned long long)i0 * DD + f0);
        f16x4 v1 = *(const f16x4*)(h + (unsigned long long)i1 * DD + f0);
        f16x4 v2 = *(const f16x4*)(h + (unsigned long long)i2 * DD + f0);
        f16x4 v3 = *(const f16x4*)(h + (unsigned long long)i3 * DD + f0);
        f16x4 v4 = *(const f16x4*)(h + (unsigned long long)i4 * DD + f0);
        f16x4 v5 = *(const f16x4*)(h + (unsigned long long)i5 * DD + f0);
        f16x4 v6 = *(const f16x4*)(h + (unsigned long long)i6 * DD + f0);
        f16x4 v7 = *(const f16x4*)(h + (unsigned long long)i7 * DD + f0);
        a0 += (((float)v0[0] + (float)v1[0]) + ((float)v2[0] + (float)v3[0])) +
              (((float)v4[0] + (float)v5[0]) + ((float)v6[0] + (float)v7[0]));
        a1 += (((float)v0[1] + (float)v1[1]) + ((float)v2[1] + (float)v3[1])) +
              (((float)v4[1] + (float)v5[1]) + ((float)v6[1] + (float)v7[1]));
        a2 += (((float)v0[2] + (float)v1[2]) + ((float)v2[2] + (float)v3[2])) +
              (((float)v4[2] + (float)v5[2]) + ((float)v6[2] + (float)v7[2]));
        a3 += (((float)v0[3] + (float)v1[3]) + ((float)v2[3] + (float)v3[3])) +
              (((float)v4[3] + (float)v5[3]) + ((float)v6[3] + (float)v7[3]));
    }
    for (; k + 4 <= cnt; k += 4) {
        int i0 = ip[k + 0], i1 = ip[k + 1], i2 = ip[k + 2], i3 = ip[k + 3];
        f16x4 v0 = *(const f16x4*)(h + (unsigned long long)i0 * DD + f0);
        f16x4 v1 = *(const f16x4*)(h + (unsigned long long)i1 * DD + f0);
        f16x4 v2 = *(const f16x4*)(h + (unsigned long long)i2 * DD + f0);
        f16x4 v3 = *(const f16x4*)(h + (unsigned long long)i3 * DD + f0);
        a0 += ((float)v0[0] + (float)v1[0]) + ((float)v2[0] + (float)v3[0]);
        a1 += ((float)v0[1] + (float)v1[1]) + ((float)v2[1] + (float)v3[1]);
        a2 += ((float)v0[2] + (float)v1[2]) + ((float)v2[2] + (float)v3[2]);
        a3 += ((float)v0[3] + (float)v1[3]) + ((float)v2[3] + (float)v3[3]);
    }
    for (; k < cnt; k++) {
        int i0 = ip[k];
        f16x4 v0 = *(const f16x4*)(h + (unsigned long long)i0 * DD + f0);
        a0 += (float)v0[0];
        a1 += (float)v0[1];
        a2 += (float)v0[2];
        a3 += (float)v0[3];
    }
    f16x4 o;
    o[0] = (_Float16)(dn * a0 + pf[f0 + 0]);
    o[1] = (_Float16)(dn * a1 + pf[f0 + 1]);
    o[2] = (_Float16)(dn * a2 + pf[f0 + 2]);
    o[3] = (_Float16)(dn * a3 + pf[f0 + 3]);
    *(f16x4*)(agg + (unsigned long long)n * DD + f0) = o;
}

/* K7a: per-block partial stats, plain stores (no atomics/fence).
   782 blocks x 64 rows; coalesced f16x8 reads; LDS reduce; 2KB partials. */
__global__ __launch_bounds__(256) void k_stats1(const _Float16* agg, float* pstat) {
    __shared__ float ls[2][DD];
    int t = threadIdx.x;
    int rg = t >> 5;  /* row group 0..7 */
    int cg = t & 31;  /* feature octet 0..31 */
    float s[8], s2[8];
#pragma unroll
    for (int j = 0; j < 8; j++) { s[j] = 0.f; s2[j] = 0.f; }
    int row0 = blockIdx.x * 64;
    int rend = row0 + 64;
    if (rend > NN) rend = NN;
    for (int r = row0 + rg; r < rend; r += 8) {
        f16x8 v = *(const f16x8*)(agg + (unsigned long long)r * DD + cg * 8);
#pragma unroll
        for (int j = 0; j < 8; j++) {
            float f = (float)v[j];
            s[j] += f;
            s2[j] += f * f;
        }
    }
    ls[0][t] = 0.f;
    ls[1][t] = 0.f;
    __syncthreads();
#pragma unroll
    for (int j = 0; j < 8; j++) {
        atomicAdd(&ls[0][cg * 8 + j], s[j]);
        atomicAdd(&ls[1][cg * 8 + j], s2[j]);
    }
    __syncthreads();
    float* pb = pstat + (unsigned long long)blockIdx.x * 512;
    pb[t] = ls[0][t];
    pb[256 + t] = ls[1][t];
}

/* K7b: final reduce over 782 partials + fin. 32 blocks; block j owns
   features j*8..j*8+7. */
__global__ __launch_bounds__(256) void k_stats2(const float* pstat, const float* pf,
                                                float* ss) {
    __shared__ float ls[16][16];
    int t = threadIdx.x;
    int r = t >> 4;
    int c = t & 15;
    int j = blockIdx.x;
    int slot = (c < 8) ? (j * 8 + c) : (256 + j * 8 + (c - 8));
    float acc = 0.f;
    for (int b = r; b < 782; b += 16)
        acc += pstat[(unsigned long long)b * 512 + slot];
    ls[r][c] = acc;
    __syncthreads();
    for (int step = 8; step >= 1; step >>= 1) {
        if (r < step) ls[r][c] += ls[r + step][c];
        __syncthreads();
    }
    if (t < 8) {
        int f = j * 8 + t;
        float sv = ls[0][t];
        float sv2 = ls[0][t + 8];
        float mean = sv * (1.0f / NN);
        float var = fmaxf(sv2 * (1.0f / NN) - mean * mean, 0.f);
        float sc = pf[DD + f] * rsqrtf(var + 1e-5f);
        ss[f] = sc;
        ss[DD + f] = pf[2 * DD + f] - mean * sc;
    }
}

/* K8: BN + ReLU: fp16 agg -> fp32 out. 8 elems/thread, grid 6250. */
__global__ void DenseGCNLayer_2937757631000_kernel(const _Float16* agg, const float* ss,
                                                   float* out) {
    int t = threadIdx.x;
    unsigned long long base =
        (unsigned long long)blockIdx.x * 2048 + (unsigned int)t * 8;
    int f = (int)(base & 255);
    f16x8 v = *(const f16x8*)(agg + base);
    f32x4 o0, o1;
#pragma unroll
    for (int j = 0; j < 4; j++)
        o0[j] = fmaxf(ss[f + j] * (float)v[j] + ss[DD + f + j], 0.f);
#pragma unroll
    for (int j = 0; j < 4; j++)
        o1[j] = fmaxf(ss[f + 4 + j] * (float)v[4 + j] + ss[DD + f + 4 + j], 0.f);
    *(f32x4*)(out + base) = o0;
    *(f32x4*)(out + base + 4) = o1;
}

extern "C" void kernel_launch(void* const* d_in, const int* in_sizes, int n_in,
                              void* d_out, int out_size, void* d_ws, size_t ws_size,
                              hipStream_t stream) {
    const void* x = d_in[0];
    const int* ei = (const int*)d_in[1];
    const void* W = d_in[2];
    const void* bias = d_in[3];
    const void* gamma = d_in[4];
    const void* beta = d_in[5];
    char* ws = (char*)d_ws;
    float* out = (float*)d_out;

    _Float16* h = (_Float16*)(ws + 0UL);          /* 25.6 MB fp16 */
    _Float16* agg = (_Float16*)(ws + 51200000UL); /* 25.6 MB fp16 */
    float* pstat = (float*)(ws + 102400000UL);    /* 1.6 MB partial stats */
    int* csrc = (int*)(ws + 108800000UL);         /* 3.2 MB */
    unsigned short* Wb = (unsigned short*)(ws + 112000000UL); /* 128 KB bf16 */
    int* deg = (int*)(ws + 112262144UL);
    float* dinv = (float*)(ws + 112462336UL);
    int* off = (int*)(ws + 112662528UL);
    int* cursor = (int*)(ws + 112862720UL);
    int* misc = (int*)(ws + 113063936UL); /* gcur, ... (16 ints) */
    float* pf = (float*)(ws + 113064960UL);
    float* ss = (float*)(ws + 113070080UL);
    int* flags = (int*)(ws + 113072128UL);

    if (ws_size < WS_NEED) {
        fprintf(stderr, "R24_WS_SMALL %zu\n", ws_size);
        fflush(stderr);
        return;
    }

    k_setup<<<453, 256, 0, stream>>>(deg, misc, (const unsigned short*)x, ei,
                                     flags, W, bias, gamma, beta, Wb, pf);
    k_edges<<<3125, 256, 0, stream>>>(ei, flags, deg);
    k_alloc<<<196, 256, 0, stream>>>(deg, off, cursor, dinv, &misc[0]);
    k_gemm<<<196, 1024, 0, stream>>>(x, flags, Wb, dinv, h);
    k_fill<<<3125, 256, 0, stream>>>(ei, flags, cursor, csrc);
    g_agg<<<12500, 256, 0, stream>>>(h, dinv, off, deg, csrc, pf, agg);
    k_stats1<<<782, 256, 0, stream>>>(agg, pstat);
    k_stats2<<<32, 256, 0, stream>>>(pstat, pf, ss);
    DenseGCNLayer_2937757631000_kernel<<<6250, 256, 0, stream>>>(agg, ss, out);
}

// Round 13
// 288.148 us; speedup vs baseline: 1.2725x; 1.1182x over previous
//
#include <hip/hip_runtime.h>
#include <cstdio>

#define NN 50000
#define NE 800000
#define DD 256
#define CAP 32
#define WS_NEED 113080000UL

__attribute__((constructor)) static void r25_on_load(void) {
    fprintf(stderr, "R25SO_LOADED\n");
    fflush(stderr);
}

__device__ float b2f(unsigned short u) {
    union { unsigned int i; float f; } c;
    c.i = ((unsigned int)u) << 16;
    return c.f;
}
__device__ float clampf(float v) { return fminf(fmaxf(v, -65504.f), 65504.f); }
__device__ float rdF(const void* p, long long idx, int ff) {
    if (ff) return clampf(b2f(((const unsigned short*)p)[idx]));
    return clampf(((const float*)p)[idx]);
}
__device__ unsigned short f2b_rne(float f) {
    union { float f; unsigned int u; } c;
    c.f = f;
    unsigned int r = (c.u + 0x7FFFu + ((c.u >> 16) & 1u)) >> 16;
    return (unsigned short)r;
}

typedef __attribute__((ext_vector_type(8))) short bf16x8;
typedef __attribute__((ext_vector_type(4))) float f32x4;
typedef __attribute__((ext_vector_type(4))) _Float16 f16x4;
typedef __attribute__((ext_vector_type(8))) _Float16 f16x8;

/* per-block x-dtype detect (2KB read, LDS count) */
__device__ int detect_ff(const unsigned short* xr) {
    __shared__ int dacc;
    if (threadIdx.x == 0) dacc = 0;
    __syncthreads();
    int g = 0;
    for (int j = 0; j < 4; j++) {
        unsigned short u = xr[(threadIdx.x * 4 + j) * 2];
        int e = (u >> 7) & 0xFF;
        if (u == 0 || u == 0x8000 || (e >= 100 && e <= 140)) g++;
    }
    atomicAdd(&dacc, g);
    __syncthreads();
    return dacc >= 922;
}

/* K1: zero (cnt/misc) + dtype detect + W->bf16 + params->fp32. */
__global__ void k_setup(int* cnt, int* misc, const unsigned short* xr,
                        const int* ei, int* flags, const void* W, const void* bias,
                        const void* gamma, const void* beta, unsigned short* Wb,
                        float* pf) {
    int b = blockIdx.x;
    int t = threadIdx.x;
    if (b < 196) {
        int i = b * 256 + t;
        if (i < NN) cnt[i] = 0;
        if (i < 16) misc[i] = 0;
        return;
    }
    if (b == 196) {
        __shared__ int acc2;
        if (t == 0) acc2 = 0;
        int ff = detect_ff(xr); /* has its own syncthreads */
        if (ei[2 * t + 1] != 0) atomicAdd(&acc2, 1);
        __syncthreads();
        if (t == 0) {
            flags[0] = ff;
            flags[1] = (acc2 == 0) ? 1 : 0; /* 1 => int64 edges */
        }
        pf[t] = rdF(bias, t, ff);
        pf[DD + t] = rdF(gamma, t, ff);
        pf[2 * DD + t] = rdF(beta, t, ff);
        return;
    }
    int ff = detect_ff(xr);
    int i = (b - 197) * 256 + t;
    Wb[i] = f2b_rne(rdF(W, i, ff));
}

/* K2: ONE-PASS CSR (R25). Static capacity CAP=32 per node (base n*32):
   no degree pre-pass, no scan — k_edges and k_alloc deleted. Overflow
   (Poisson(16): P(deg>32)~1e-4) appends (c,r) pairs to ovf (sized NE,
   never drops). cnt[] doubles as the degree array for dinv. */
__global__ void k_fill1(const int* raw, const int* flags, int* cnt, int* csrc,
                        int* ovf, int* novf) {
    int e = blockIdx.x * 256 + threadIdx.x;
    if (e >= NE) return;
    int f = flags[1];
    int r = f ? raw[2 * e] : raw[e];
    int c = f ? raw[2 * (NE + e)] : raw[NE + e];
    if ((unsigned int)c < NN && (unsigned int)r < NN) {
        int slot = atomicAdd(&cnt[c], 1);
        if (slot < CAP) {
            csrc[c * CAP + slot] = r;
        } else {
            int o = atomicAdd(novf, 1);
            ovf[2 * o] = c;
            ovf[2 * o + 1] = r;
        }
    }
}

/* K3: dinv from cnt (true degree). */
__global__ void k_dinv(const int* cnt, float* dinv) {
    int i = blockIdx.x * 256 + threadIdx.x;
    if (i < NN) dinv[i] = rsqrtf((float)(cnt[i] + 1));
}

/* K4: MFMA GEMM, FULL-W LDS. Block = 1024 thr = 16 waves x 16 rows;
   W (256x256 bf16) in 132 KB LDS (528B pitch). Grid 196, x read once.
   h' = dinv[n] * (x @ W^T), fp32 acc, fp16 store.
   C/D: col = lane&15, row = (lane>>4)*4 + reg  (m89-verified mapping) */
#define WP 264 /* LDS row pitch in shorts (512B data + 16B pad) */
__global__ __launch_bounds__(1024) void k_gemm(const void* x, const int* flags,
                                               const unsigned short* Wb,
                                               const float* dinv, _Float16* h) {
    __shared__ unsigned short wlds[256 * WP]; /* 135168 B */
    int t = threadIdx.x;

#pragma unroll
    for (int i = 0; i < 8; i++) {
        int c = t + i * 1024;
        int row = c >> 5;
        int off = (c & 31) * 8;
        bf16x8 v = *(const bf16x8*)(Wb + row * DD + off);
        *(bf16x8*)(&wlds[row * WP + off]) = v;
    }
    __syncthreads();

    int wave = t >> 6;
    int lane = t & 63;
    int rw = blockIdx.x * 16 + wave;
    if (rw >= 3125) return; /* after barrier: safe */
    int r0 = rw * 16;
    int l15 = lane & 15;
    int kq = lane >> 4;

    bf16x8 a[8];
    int ff = flags[0];
    if (ff) {
        const unsigned short* p =
            (const unsigned short*)x + (unsigned long long)(r0 + l15) * DD + kq * 8;
#pragma unroll
        for (int k = 0; k < 8; k++)
            a[k] = *(const bf16x8*)(p + k * 32);
    } else {
        const float* p = (const float*)x + (unsigned long long)(r0 + l15) * DD + kq * 8;
#pragma unroll
        for (int k = 0; k < 8; k++) {
#pragma unroll
            for (int j = 0; j < 8; j++)
                a[k][j] = (short)f2b_rne(p[k * 32 + j]);
        }
    }

    float dv[4];
#pragma unroll
    for (int j = 0; j < 4; j++) dv[j] = dinv[r0 + kq * 4 + j];

#pragma unroll
    for (int ct = 0; ct < 16; ct++) {
        f32x4 acc = {0.f, 0.f, 0.f, 0.f};
#pragma unroll
        for (int k = 0; k < 8; k++) {
            bf16x8 b = *(const bf16x8*)(&wlds[(ct * 16 + l15) * WP + kq * 8 + k * 32]);
            acc = __builtin_amdgcn_mfma_f32_16x16x32_bf16(a[k], b, acc, 0, 0, 0);
        }
        _Float16* op = h + (unsigned long long)(r0 + kq * 4) * DD + ct * 16 + l15;
#pragma unroll
        for (int j = 0; j < 4; j++)
            op[(unsigned long long)j * DD] = (_Float16)(acc[j] * dv[j]);
    }
}

/* K5: aggregate + bias -> fp16 agg. one node per wave, 8-deep ILP unroll.
   Static base n*CAP; overflow nodes (cnt>CAP) scan the tiny ovf list. */
__global__ __launch_bounds__(256) void g_agg(const _Float16* h, const float* dinv,
                                             const int* cnt, const int* csrc,
                                             const int* ovf, const int* novf,
                                             const float* pf, _Float16* agg) {
    int lane = threadIdx.x & 63;
    int n = blockIdx.x * 4 + (threadIdx.x >> 6);
    int f0 = lane * 4;
    int cn = __builtin_amdgcn_readfirstlane(cnt[n]);
    int m = (cn < CAP) ? cn : CAP;
    float dn = dinv[n];
    f16x4 hv = *(const f16x4*)(h + (unsigned long long)n * DD + f0);
    float a0 = (float)hv[0];
    float a1 = (float)hv[1];
    float a2 = (float)hv[2];
    float a3 = (float)hv[3];
    const int* ip = csrc + n * CAP;
    int k = 0;
    for (; k + 8 <= m; k += 8) {
        int i0 = ip[k + 0], i1 = ip[k + 1], i2 = ip[k + 2], i3 = ip[k + 3];
        int i4 = ip[k + 4], i5 = ip[k + 5], i6 = ip[k + 6], i7 = ip[k + 7];
        f16x4 v0 = *(const f16x4*)(h + (unsigned long long)i0 * DD + f0);
        f16x4 v1 = *(const f16x4*)(h + (unsigned long long)i1 * DD + f0);
        f16x4 v2 = *(const f16x4*)(h + (unsigned long long)i2 * DD + f0);
        f16x4 v3 = *(const f16x4*)(h + (unsigned long long)i3 * DD + f0);
        f16x4 v4 = *(const f16x4*)(h + (unsigned long long)i4 * DD + f0);
        f16x4 v5 = *(const f16x4*)(h + (unsigned long long)i5 * DD + f0);
        f16x4 v6 = *(const f16x4*)(h + (unsigned long long)i6 * DD + f0);
        f16x4 v7 = *(const f16x4*)(h + (unsigned long long)i7 * DD + f0);
        a0 += (((float)v0[0] + (float)v1[0]) + ((float)v2[0] + (float)v3[0])) +
              (((float)v4[0] + (float)v5[0]) + ((float)v6[0] + (float)v7[0]));
        a1 += (((float)v0[1] + (float)v1[1]) + ((float)v2[1] + (float)v3[1])) +
              (((float)v4[1] + (float)v5[1]) + ((float)v6[1] + (float)v7[1]));
        a2 += (((float)v0[2] + (float)v1[2]) + ((float)v2[2] + (float)v3[2])) +
              (((float)v4[2] + (float)v5[2]) + ((float)v6[2] + (float)v7[2]));
        a3 += (((float)v0[3] + (float)v1[3]) + ((float)v2[3] + (float)v3[3])) +
              (((float)v4[3] + (float)v5[3]) + ((float)v6[3] + (float)v7[3]));
    }
    for (; k + 4 <= m; k += 4) {
        int i0 = ip[k + 0], i1 = ip[k + 1], i2 = ip[k + 2], i3 = ip[k + 3];
        f16x4 v0 = *(const f16x4*)(h + (unsigned long long)i0 * DD + f0);
        f16x4 v1 = *(const f16x4*)(h + (unsigned long long)i1 * DD + f0);
        f16x4 v2 = *(const f16x4*)(h + (unsigned long long)i2 * DD + f0);
        f16x4 v3 = *(const f16x4*)(h + (unsigned long long)i3 * DD + f0);
        a0 += ((float)v0[0] + (float)v1[0]) + ((float)v2[0] + (float)v3[0]);
        a1 += ((float)v0[1] + (float)v1[1]) + ((float)v2[1] + (float)v3[1]);
        a2 += ((float)v0[2] + (float)v1[2]) + ((float)v2[2] + (float)v3[2]);
        a3 += ((float)v0[3] + (float)v1[3]) + ((float)v2[3] + (float)v3[3]);
    }
    for (; k < m; k++) {
        int i0 = ip[k];
        f16x4 v0 = *(const f16x4*)(h + (unsigned long long)i0 * DD + f0);
        a0 += (float)v0[0];
        a1 += (float)v0[1];
        a2 += (float)v0[2];
        a3 += (float)v0[3];
    }
    if (cn > CAP) { /* rare: scan overflow list (broadcast loads) */
        int no = __builtin_amdgcn_readfirstlane(*novf);
        for (int i = 0; i < no; i++) {
            if (ovf[2 * i] == n) {
                int r = ovf[2 * i + 1];
                f16x4 v0 = *(const f16x4*)(h + (unsigned long long)r * DD + f0);
                a0 += (float)v0[0];
                a1 += (float)v0[1];
                a2 += (float)v0[2];
                a3 += (float)v0[3];
            }
        }
    }
    f16x4 o;
    o[0] = (_Float16)(dn * a0 + pf[f0 + 0]);
    o[1] = (_Float16)(dn * a1 + pf[f0 + 1]);
    o[2] = (_Float16)(dn * a2 + pf[f0 + 2]);
    o[3] = (_Float16)(dn * a3 + pf[f0 + 3]);
    *(f16x4*)(agg + (unsigned long long)n * DD + f0) = o;
}

/* K6a: per-block partial stats, plain stores (no atomics/fence). */
__global__ __launch_bounds__(256) void k_stats1(const _Float16* agg, float* pstat) {
    __shared__ float ls[2][DD];
    int t = threadIdx.x;
    int rg = t >> 5;  /* row group 0..7 */
    int cg = t & 31;  /* feature octet 0..31 */
    float s[8], s2[8];
#pragma unroll
    for (int j = 0; j < 8; j++) { s[j] = 0.f; s2[j] = 0.f; }
    int row0 = blockIdx.x * 64;
    int rend = row0 + 64;
    if (rend > NN) rend = NN;
    for (int r = row0 + rg; r < rend; r += 8) {
        f16x8 v = *(const f16x8*)(agg + (unsigned long long)r * DD + cg * 8);
#pragma unroll
        for (int j = 0; j < 8; j++) {
            float f = (float)v[j];
            s[j] += f;
            s2[j] += f * f;
        }
    }
    ls[0][t] = 0.f;
    ls[1][t] = 0.f;
    __syncthreads();
#pragma unroll
    for (int j = 0; j < 8; j++) {
        atomicAdd(&ls[0][cg * 8 + j], s[j]);
        atomicAdd(&ls[1][cg * 8 + j], s2[j]);
    }
    __syncthreads();
    float* pb = pstat + (unsigned long long)blockIdx.x * 512;
    pb[t] = ls[0][t];
    pb[256 + t] = ls[1][t];
}

/* K6b: final reduce over 782 partials + fin. 32 blocks. */
__global__ __launch_bounds__(256) void k_stats2(const float* pstat, const float* pf,
                                                float* ss) {
    __shared__ float ls[16][16];
    int t = threadIdx.x;
    int r = t >> 4;
    int c = t & 15;
    int j = blockIdx.x;
    int slot = (c < 8) ? (j * 8 + c) : (256 + j * 8 + (c - 8));
    float acc = 0.f;
    for (int b = r; b < 782; b += 16)
        acc += pstat[(unsigned long long)b * 512 + slot];
    ls[r][c] = acc;
    __syncthreads();
    for (int step = 8; step >= 1; step >>= 1) {
        if (r < step) ls[r][c] += ls[r + step][c];
        __syncthreads();
    }
    if (t < 8) {
        int f = j * 8 + t;
        float sv = ls[0][t];
        float sv2 = ls[0][t + 8];
        float mean = sv * (1.0f / NN);
        float var = fmaxf(sv2 * (1.0f / NN) - mean * mean, 0.f);
        float sc = pf[DD + f] * rsqrtf(var + 1e-5f);
        ss[f] = sc;
        ss[DD + f] = pf[2 * DD + f] - mean * sc;
    }
}

/* K7: BN + ReLU: fp16 agg -> fp32 out. 8 elems/thread, grid 6250. */
__global__ void DenseGCNLayer_2937757631000_kernel(const _Float16* agg, const float* ss,
                                                   float* out) {
    int t = threadIdx.x;
    unsigned long long base =
        (unsigned long long)blockIdx.x * 2048 + (unsigned int)t * 8;
    int f = (int)(base & 255);
    f16x8 v = *(const f16x8*)(agg + base);
    f32x4 o0, o1;
#pragma unroll
    for (int j = 0; j < 4; j++)
        o0[j] = fmaxf(ss[f + j] * (float)v[j] + ss[DD + f + j], 0.f);
#pragma unroll
    for (int j = 0; j < 4; j++)
        o1[j] = fmaxf(ss[f + 4 + j] * (float)v[4 + j] + ss[DD + f + 4 + j], 0.f);
    *(f32x4*)(out + base) = o0;
    *(f32x4*)(out + base + 4) = o1;
}

extern "C" void kernel_launch(void* const* d_in, const int* in_sizes, int n_in,
                              void* d_out, int out_size, void* d_ws, size_t ws_size,
                              hipStream_t stream) {
    const void* x = d_in[0];
    const int* ei = (const int*)d_in[1];
    const void* W = d_in[2];
    const void* bias = d_in[3];
    const void* gamma = d_in[4];
    const void* beta = d_in[5];
    char* ws = (char*)d_ws;
    float* out = (float*)d_out;

    _Float16* h = (_Float16*)(ws + 0UL);          /* 25.6 MB fp16 */
    _Float16* agg = (_Float16*)(ws + 51200000UL); /* 25.6 MB fp16 */
    int* ovf = (int*)(ws + 80000000UL);           /* 6.4 MB overflow pairs */
    float* pstat = (float*)(ws + 102400000UL);    /* 1.6 MB partial stats */
    int* csrc = (int*)(ws + 104800000UL);         /* 6.4 MB (CAP=32) */
    unsigned short* Wb = (unsigned short*)(ws + 112000000UL); /* 128 KB bf16 */
    int* cnt = (int*)(ws + 112262144UL);
    float* dinv = (float*)(ws + 112462336UL);
    int* misc = (int*)(ws + 113063936UL); /* [0]=novf, ... (16 ints) */
    float* pf = (float*)(ws + 113064960UL);
    float* ss = (float*)(ws + 113070080UL);
    int* flags = (int*)(ws + 113072128UL);

    if (ws_size < WS_NEED) {
        fprintf(stderr, "R25_WS_SMALL %zu\n", ws_size);
        fflush(stderr);
        return;
    }

    k_setup<<<453, 256, 0, stream>>>(cnt, misc, (const unsigned short*)x, ei,
                                     flags, W, bias, gamma, beta, Wb, pf);
    k_fill1<<<3125, 256, 0, stream>>>(ei, flags, cnt, csrc, ovf, &misc[0]);
    k_dinv<<<196, 256, 0, stream>>>(cnt, dinv);
    k_gemm<<<196, 1024, 0, stream>>>(x, flags, Wb, dinv, h);
    g_agg<<<12500, 256, 0, stream>>>(h, dinv, cnt, csrc, ovf, &misc[0], pf, agg);
    k_stats1<<<782, 256, 0, stream>>>(agg, pstat);
    k_stats2<<<32, 256, 0, stream>>>(pstat, pf, ss);
    DenseGCNLayer_2937757631000_kernel<<<6250, 256, 0, stream>>>(agg, ss, out);
}